// Round 4
// baseline (1614.797 us; speedup 1.0000x reference)
//
#include <hip/hip_runtime.h>
#include <math.h>

constexpr int V_ = 50000, D_ = 128, B_ = 1024, P_ = 50;
constexpr int N_ = 51200, E_ = 51200;
constexpr long long NS_ = (long long)N_ * D_;
constexpr float SCALE_ = 12.0f;

typedef __attribute__((ext_vector_type(8))) unsigned short u16x8;
typedef __attribute__((ext_vector_type(8))) __bf16 bf16x8;
typedef __attribute__((ext_vector_type(4))) float f32x4;

static __device__ __forceinline__ float wsum(float v) {
    #pragma unroll
    for (int o = 32; o; o >>= 1) v += __shfl_xor(v, o, 64);
    return v;
}
static __device__ __forceinline__ float wmax(float v) {
    #pragma unroll
    for (int o = 32; o; o >>= 1) v = fmaxf(v, __shfl_xor(v, o, 64));
    return v;
}
static __device__ __forceinline__ float sig(float x) { return 1.f / (1.f + expf(-x)); }

// fp32 -> bf16 round-to-nearest-even
static __device__ __forceinline__ unsigned short f2b(float x) {
    unsigned u = __float_as_uint(x);
    u += 0x7fffu + ((u >> 16) & 1u);
    return (unsigned short)(u >> 16);
}

// ---------------- dt = max(edge_t) ----------------
__global__ void k_dtmax(const float* __restrict__ et, float* __restrict__ dt) {
    __shared__ float s[256];
    float m = 0.f;
    for (int i = threadIdx.x; i < E_; i += 256) m = fmaxf(m, et[i]);
    s[threadIdx.x] = m; __syncthreads();
    for (int o = 128; o; o >>= 1) {
        if (threadIdx.x < o) s[threadIdx.x] = fmaxf(s[threadIdx.x], s[threadIdx.x + o]);
        __syncthreads();
    }
    if (threadIdx.x == 0) *dt = s[0];
}

// ---------------- feat = normalize(embedding[iid]) ----------------
__global__ void k_feat0(const float* __restrict__ emb, const int* __restrict__ iid,
                        float* __restrict__ feat) {
    int row = blockIdx.x * 4 + (threadIdx.x >> 6);
    int l = threadIdx.x & 63;
    const float* p = emb + (long long)iid[row] * D_;
    float a = p[l], b = p[l + 64];
    float ss = wsum(a * a + b * b);
    float s = 1.f / (sqrtf(ss) + 1e-12f);
    float* q = feat + (long long)row * D_;
    q[l] = a * s; q[l + 64] = b * s;
}

// ---------------- stage-A per-graph weighted aggregation ----------------
__global__ void k_aggA_g(const int* __restrict__ esrc, const int* __restrict__ edst,
                         const float* __restrict__ ew, const float* __restrict__ feat,
                         float* __restrict__ m_in, float* __restrict__ m_out) {
    __shared__ float sfeat[P_ * D_];
    __shared__ float smin[P_ * D_];
    __shared__ float smout[P_ * D_];
    __shared__ int ses[P_], sed[P_];
    __shared__ float sw[P_], swin[P_], swout[P_];
    int g = blockIdx.x, t = threadIdx.x;
    int n0 = g * P_;
    long long base = (long long)n0 * D_;
    for (int i = t; i < P_ * D_; i += 256) {
        sfeat[i] = feat[base + i];
        smin[i] = 0.f; smout[i] = 0.f;
    }
    if (t < P_) {
        int E0 = g * P_ + t;
        ses[t] = esrc[E0] - n0;
        sed[t] = edst[E0] - n0;
        sw[t] = ew[E0];
    }
    __syncthreads();
    int d = t & 127;
    for (int e = 0; e < P_; e++) {
        int ls = ses[e], ld = sed[e];
        float w = sw[e];
        if (t < 128) smin[ld * D_ + d] += sfeat[ls * D_ + d] * w;
        else         smout[ls * D_ + d] += sfeat[ld * D_ + d] * w;
    }
    if (t < P_) {
        float wi = 0.f, wo = 0.f;
        for (int e = 0; e < P_; e++) {
            if (sed[e] == t) wi += sw[e];
            if (ses[e] == t) wo += sw[e];
        }
        swin[t] = (wi > 0.f) ? 1.f / wi : 1.f;
        swout[t] = (wo > 0.f) ? 1.f / wo : 1.f;
    }
    __syncthreads();
    for (int i = t; i < P_ * D_; i += 256) {
        int n = i >> 7;
        m_in[base + i] = smin[i] * swin[n];
        m_out[base + i] = smout[i] * swout[n];
    }
}

// ---------------- per-graph GCN aggregation via LDS CSR gather ----------------
// MODE0: out1 = D(a1) [if a1], out2 = D(a2) [if a2];  MODE1: out1 = D(a1*a2)
// D(v) = nrm * seg_sum(v * nrm) over masked symmetric edges.
template<int MODE>
__launch_bounds__(256)
__global__ void k_gagg2(const int* __restrict__ esrc, const int* __restrict__ edst,
                        const float* __restrict__ et, const float* __restrict__ dtp, float tfac,
                        const float* __restrict__ a1, const float* __restrict__ a2,
                        float* __restrict__ out1, float* __restrict__ out2) {
    constexpr int NSV = (MODE == 0) ? 2 : 1;
    __shared__ float sv[NSV * P_ * D_];
    __shared__ int ses[P_], sed[P_];
    __shared__ float snrm[P_];
    __shared__ int sdeg[P_], soff[P_ + 1];
    __shared__ int snbr[2 * P_];
    int g = blockIdx.x, t = threadIdx.x;
    int n0 = g * P_;
    long long base = (long long)n0 * D_;
    float tv = tfac * dtp[0];
    if (t < P_) {
        int E0 = g * P_ + t;
        int s = esrc[E0], dd = edst[E0];
        bool ml = (s != dd) && (et[E0] <= tv);
        ses[t] = ml ? (s - n0) : -1;
        sed[t] = ml ? (dd - n0) : -1;
    }
    __syncthreads();
    if (t < P_) {
        int deg = 0;
        for (int e = 0; e < P_; e++) deg += (ses[e] == t) + (sed[e] == t);
        sdeg[t] = deg;
        snrm[t] = rsqrtf(fmaxf((float)deg, 1.f));
    }
    __syncthreads();
    if (t == 0) {
        int off = 0;
        for (int n = 0; n < P_; n++) { soff[n] = off; off += sdeg[n]; }
        soff[P_] = off;
    }
    __syncthreads();
    if (t < P_) {
        int c = soff[t];
        for (int e = 0; e < P_; e++) {
            if (ses[e] == t) snbr[c++] = sed[e];
            if (sed[e] == t) snbr[c++] = ses[e];
        }
    }
    // load scaled values
    float* sv1 = sv;
    float* sv2 = sv + P_ * D_;
    for (int i = t; i < P_ * D_; i += 256) {
        int n = i >> 7;
        if (MODE == 1) {
            sv1[i] = a1[base + i] * a2[base + i] * snrm[n];
        } else {
            sv1[i] = a1 ? a1[base + i] * snrm[n] : 0.f;
            if (a2) sv2[i] = a2[base + i] * snrm[n];
        }
    }
    __syncthreads();
    // gather: thread (half, d) handles 25 nodes for dim d
    int d = t & 127;
    int nlo = (t >> 7) * 25;
    bool two = (MODE == 0) && (a2 != nullptr);
    bool one = (MODE == 1) || (a1 != nullptr);
    for (int n = nlo; n < nlo + 25; n++) {
        float s1 = 0.f, s2 = 0.f;
        int j0 = soff[n], j1 = soff[n + 1];
        for (int j = j0; j < j1; j++) {
            int nb = snbr[j];
            s1 += sv1[nb * D_ + d];
            if (two) s2 += sv2[nb * D_ + d];
        }
        float nr = snrm[n];
        long long o = base + (long long)n * D_ + d;
        if (one) out1[o] = s1 * nr;
        if (two) out2[o] = s2 * nr;
    }
}

// ---- precompute: BM[k][512] = folded (W @ wih-chunk) with rz/inn/hnn column layout ----
// BM[k][j] = sum_c W[k][c]*wih[j][coff+c] for j<384; 0 for j>=384.
__global__ void k_prec512(const float* __restrict__ W, const float* __restrict__ wih, int coff,
                          float* __restrict__ BM) {
    int idx = blockIdx.x * 256 + threadIdx.x;
    if (idx >= 128 * 512) return;
    int k = idx >> 9, j = idx & 511;
    float s = 0.f;
    if (j < 384) {
        const float* wr = W + (long long)k * 256;
        const float* ir = wih + (long long)j * 512 + coff;
        for (int c = 0; c < 256; c++) s += wr[c] * ir[c];
    }
    BM[idx] = s;
}

// BM3[k][j]: j<256 -> whh[j][k]; 256<=j<384 -> 0; j>=384 -> whh[j-128][k]
__global__ void k_prec3(const float* __restrict__ whh, float* __restrict__ BM3) {
    int idx = blockIdx.x * 256 + threadIdx.x;
    if (idx >= 128 * 512) return;
    int k = idx >> 9, j = idx & 511;
    float v = 0.f;
    if (j < 256) v = whh[(long long)j * 128 + k];
    else if (j >= 384) v = whh[(long long)(j - 128) * 128 + k];
    BM3[idx] = v;
}

// bias512: j<256: bih[j]+bhh[j]; j<384: bih[j]; else bhh[j-128]
__global__ void k_bias512(const float* __restrict__ bih, const float* __restrict__ bhh,
                          float* __restrict__ b512) {
    int j = blockIdx.x * 256 + threadIdx.x;
    if (j >= 512) return;
    float v;
    if (j < 256) v = bih[j] + bhh[j];
    else if (j < 384) v = bih[j];
    else v = bhh[j - 128];
    b512[j] = v;
}

// ---------------- MFMA bf16 GEMM, segmented A/B (NA segments of K=128 each) --------
// C = act( sum_s A_s @ B_s + bias1 + bias2 ).  B_s row-major [k][ldb].
template<int NA, int ACT>
__launch_bounds__(256)
__global__ void k_mm(const float* __restrict__ A1, const float* __restrict__ A2,
                     const float* __restrict__ A3,
                     const float* __restrict__ B1, const float* __restrict__ B2,
                     const float* __restrict__ B3, int ldb,
                     const float* __restrict__ bias1, const float* __restrict__ bias2,
                     float* __restrict__ C, int ncols, long long ldc) {
    __shared__ unsigned short As[128 * 40];
    __shared__ unsigned short Bs[128 * 40];
    const int t = threadIdx.x;
    const int bm = blockIdx.y, bn = blockIdx.x;
    const int lane = t & 63, wid = t >> 6;
    const int wr = wid >> 1, wc = wid & 1;
    const int lr = lane & 15, lh = lane >> 4;
    f32x4 acc[4][4] = {};
    constexpr int KTOT = NA * 128;
    for (int ks = 0; ks < KTOT; ks += 32) {
        #pragma unroll
        for (int i = 0; i < 4; i++) {
            int idx = i * 256 + t;
            int row = idx >> 3, kl = (idx & 7) * 4;
            int gk = ks + kl;
            int seg = gk >> 7, ak = gk & 127;
            const float* Ap = (NA == 1) ? A1 : (seg == 0 ? A1 : (seg == 1 ? A2 : A3));
            float4 v = *(const float4*)&Ap[((long long)bm * 128 + row) * 128 + ak];
            ushort4 bb; bb.x = f2b(v.x); bb.y = f2b(v.y); bb.z = f2b(v.z); bb.w = f2b(v.w);
            *(ushort4*)&As[row * 40 + kl] = bb;
        }
        #pragma unroll
        for (int i = 0; i < 16; i++) {
            int idx = i * 256 + t;
            int col = idx & 127, kl = idx >> 7;
            int gk = ks + kl;
            int seg = gk >> 7, bk = gk & 127;
            const float* Bp = (NA == 1) ? B1 : (seg == 0 ? B1 : (seg == 1 ? B2 : B3));
            int gcol = bn * 128 + col;
            float v = (gcol < ncols) ? Bp[(long long)bk * ldb + gcol] : 0.f;
            Bs[col * 40 + kl] = f2b(v);
        }
        __syncthreads();
        bf16x8 af[4], bf[4];
        #pragma unroll
        for (int f = 0; f < 4; f++) {
            u16x8 ar = *(const u16x8*)&As[(wr * 64 + f * 16 + lr) * 40 + lh * 8];
            u16x8 br = *(const u16x8*)&Bs[(wc * 64 + f * 16 + lr) * 40 + lh * 8];
            af[f] = __builtin_bit_cast(bf16x8, ar);
            bf[f] = __builtin_bit_cast(bf16x8, br);
        }
        #pragma unroll
        for (int fr = 0; fr < 4; fr++)
            #pragma unroll
            for (int fc = 0; fc < 4; fc++)
                acc[fr][fc] = __builtin_amdgcn_mfma_f32_16x16x32_bf16(af[fr], bf[fc], acc[fr][fc], 0, 0, 0);
        __syncthreads();
    }
    #pragma unroll
    for (int fc = 0; fc < 4; fc++) {
        int col = bn * 128 + wc * 64 + fc * 16 + lr;
        if (col >= ncols) continue;
        float bb = (bias1 ? bias1[col] : 0.f) + (bias2 ? bias2[col] : 0.f);
        #pragma unroll
        for (int fr = 0; fr < 4; fr++) {
            long long row0 = (long long)bm * 128 + wr * 64 + fr * 16 + lh * 4;
            #pragma unroll
            for (int r = 0; r < 4; r++) {
                float v = acc[fr][fc][r] + bb;
                if (ACT == 1) v = sig(v);
                else if (ACT == 2) v = tanhf(v);
                C[(row0 + r) * ldc + col] = v;
            }
        }
    }
}

// ---------------- u-GEMM with fused dh/acc/h update ----------------
// u = tanh(A1@B1 + A2@B2 + b1 + b2); v = (1-z)(u-h); dh = v/max(||v||,eps);
// acc += accw*dh; h = feat + hfac*dt*dh
__launch_bounds__(256)
__global__ void k_u_dhu(const float* __restrict__ A1, const float* __restrict__ A2,
                        const float* __restrict__ B1, const float* __restrict__ B2,
                        const float* __restrict__ bias1, const float* __restrict__ bias2,
                        const float* __restrict__ zb, const float* __restrict__ feat,
                        float* __restrict__ acc_g, float* __restrict__ h_g,
                        const float* __restrict__ dtp, float accw, float hfac, int first) {
    __shared__ unsigned short As[128 * 40];
    __shared__ unsigned short Bs[128 * 40];
    __shared__ float ssq[128];
    const int t = threadIdx.x;
    const int bm = blockIdx.y;
    const int lane = t & 63, wid = t >> 6;
    const int wr = wid >> 1, wc = wid & 1;
    const int lr = lane & 15, lh = lane >> 4;
    f32x4 acc[4][4] = {};
    for (int ks = 0; ks < 256; ks += 32) {
        #pragma unroll
        for (int i = 0; i < 4; i++) {
            int idx = i * 256 + t;
            int row = idx >> 3, kl = (idx & 7) * 4;
            int gk = ks + kl;
            const float* Ap = (gk < 128) ? A1 : A2;
            int ak = gk & 127;
            float4 v = *(const float4*)&Ap[((long long)bm * 128 + row) * 128 + ak];
            ushort4 bb; bb.x = f2b(v.x); bb.y = f2b(v.y); bb.z = f2b(v.z); bb.w = f2b(v.w);
            *(ushort4*)&As[row * 40 + kl] = bb;
        }
        #pragma unroll
        for (int i = 0; i < 16; i++) {
            int idx = i * 256 + t;
            int col = idx & 127, kl = idx >> 7;
            int gk = ks + kl;
            const float* Bp = (gk < 128) ? B1 : B2;
            int bk = gk & 127;
            float v = Bp[(long long)bk * 128 + col];
            Bs[col * 40 + kl] = f2b(v);
        }
        __syncthreads();
        bf16x8 af[4], bf[4];
        #pragma unroll
        for (int f = 0; f < 4; f++) {
            u16x8 ar = *(const u16x8*)&As[(wr * 64 + f * 16 + lr) * 40 + lh * 8];
            u16x8 br = *(const u16x8*)&Bs[(wc * 64 + f * 16 + lr) * 40 + lh * 8];
            af[f] = __builtin_bit_cast(bf16x8, ar);
            bf[f] = __builtin_bit_cast(bf16x8, br);
        }
        #pragma unroll
        for (int fr = 0; fr < 4; fr++)
            #pragma unroll
            for (int fc = 0; fc < 4; fc++)
                acc[fr][fc] = __builtin_amdgcn_mfma_f32_16x16x32_bf16(af[fr], bf[fc], acc[fr][fc], 0, 0, 0);
        __syncthreads();
    }
    if (t < 128) ssq[t] = 0.f;
    __syncthreads();
    float pr[4][4] = {};
    #pragma unroll
    for (int fc = 0; fc < 4; fc++) {
        int col = wc * 64 + fc * 16 + lr;
        float bb = bias1[col] + bias2[col];
        #pragma unroll
        for (int fr = 0; fr < 4; fr++) {
            long long rb = ((long long)bm * 128 + wr * 64 + fr * 16 + lh * 4) * 128 + col;
            #pragma unroll
            for (int r = 0; r < 4; r++) {
                long long ix = rb + (long long)r * 128;
                float u = tanhf(acc[fr][fc][r] + bb);
                float z = zb[ix], hh = h_g[ix];
                float v = (1.f - z) * (u - hh);
                acc[fr][fc][r] = v;
                pr[fr][r] += v * v;
            }
        }
    }
    #pragma unroll
    for (int fr = 0; fr < 4; fr++)
        #pragma unroll
        for (int r = 0; r < 4; r++)
            atomicAdd(&ssq[wr * 64 + fr * 16 + lh * 4 + r], pr[fr][r]);
    __syncthreads();
    float dt = dtp[0];
    #pragma unroll
    for (int fr = 0; fr < 4; fr++) {
        int rowl0 = wr * 64 + fr * 16 + lh * 4;
        #pragma unroll
        for (int r = 0; r < 4; r++) {
            float s = 1.f / fmaxf(sqrtf(ssq[rowl0 + r]), 1e-12f);
            #pragma unroll
            for (int fc = 0; fc < 4; fc++) {
                int col = wc * 64 + fc * 16 + lr;
                long long ix = ((long long)bm * 128 + rowl0 + r) * 128 + col;
                float kv = acc[fr][fc][r] * s;
                float an = (first ? 0.f : acc_g[ix]) + accw * kv;
                acc_g[ix] = an;
                if (hfac != 0.f) h_g[ix] = feat[ix] + hfac * dt * kv;
            }
        }
    }
}

// ---------------- GRU (fused gi+gh layout: [r|z|inn|hnn] x 128) + renorm ------------
__global__ void k_gru2(const float* __restrict__ gih, float* __restrict__ feat) {
    int row = blockIdx.x * 4 + (threadIdx.x >> 6);
    int l = threadIdx.x & 63;
    const float* g = gih + (long long)row * 512;
    float* fr = feat + (long long)row * 128;
    float nv[2]; float ss = 0.f;
    #pragma unroll
    for (int tq = 0; tq < 2; tq++) {
        int d = l + tq * 64;
        float r = sig(g[d]);
        float z = sig(g[128 + d]);
        float n = tanhf(g[256 + d] + r * g[384 + d]);
        float fv = fr[d];
        nv[tq] = (1.f - z) * n + z * fv;
        ss += nv[tq] * nv[tq];
    }
    ss = wsum(ss);
    float s = 1.f / fmaxf(sqrtf(ss), 1e-12f);
    fr[l] = nv[0] * s; fr[l + 64] = nv[1] * s;
}

__global__ void k_fin(float* __restrict__ feat, const float* __restrict__ acc,
                      const float* __restrict__ dtp) {
    int row = blockIdx.x * 4 + (threadIdx.x >> 6);
    int l = threadIdx.x & 63;
    long long base = (long long)row * 128;
    float dt6 = (*dtp) / 6.f;
    float v0 = feat[base + l] + dt6 * acc[base + l];
    float v1 = feat[base + l + 64] + dt6 * acc[base + l + 64];
    float ss = wsum(v0 * v0 + v1 * v1);
    float s = 1.f / sqrtf(ss);
    feat[base + l] = v0 * s; feat[base + l + 64] = v1 * s;
}

// ---------------- readout ----------------
__global__ void k_fv(const float* __restrict__ feat, const int* __restrict__ last,
                     const float* __restrict__ Wv, const float* __restrict__ bv,
                     float* __restrict__ fv) {
    __shared__ float fr[128];
    int b = blockIdx.x; int j = threadIdx.x;
    fr[j] = feat[(long long)last[b] * 128 + j];
    __syncthreads();
    float s = bv[j];
    for (int k = 0; k < 128; k++) s += fr[k] * Wv[(long long)k * 128 + j];
    fv[(long long)b * 128 + j] = s;
}

__global__ void k_e(const float* __restrict__ fu, const float* __restrict__ fv,
                    const int* __restrict__ gid, const float* __restrict__ fce,
                    float* __restrict__ e) {
    int row = blockIdx.x * 4 + (threadIdx.x >> 6);
    int l = threadIdx.x & 63;
    int g = gid[row];
    float s = 0.f;
    #pragma unroll
    for (int tq = 0; tq < 2; tq++) {
        int d = l + tq * 64;
        float x = fu[(long long)row * 128 + d] + fv[(long long)g * 128 + d];
        s += sig(x) * fce[d];
    }
    s = wsum(s);
    if (l == 0) e[row] = s;
}

__global__ void k_softg(const float* __restrict__ e, float* __restrict__ alpha) {
    int b = blockIdx.x; int l = threadIdx.x;
    float v = (l < P_) ? e[b * P_ + l] : -1e30f;
    float m = wmax(v);
    float ex = (l < P_) ? expf(v - m) : 0.f;
    float s = wsum(ex);
    if (l < P_) alpha[b * P_ + l] = ex / s;
}

__global__ void k_srg(const float* __restrict__ feat, const float* __restrict__ alpha,
                      float* __restrict__ srg) {
    int b = blockIdx.x; int d = threadIdx.x;
    float s = 0.f;
    for (int p = 0; p < P_; p++)
        s += feat[(long long)(b * P_ + p) * 128 + d] * alpha[b * P_ + p];
    srg[(long long)b * 128 + d] = s;
}

__global__ void k_sr(const float* __restrict__ feat, const int* __restrict__ last,
                     const float* __restrict__ srg, const float* __restrict__ Wsr,
                     float* __restrict__ sr) {
    __shared__ float in[256];
    __shared__ float red[2];
    int b = blockIdx.x; int j = threadIdx.x;
    in[j] = feat[(long long)last[b] * 128 + j];
    in[128 + j] = srg[(long long)b * 128 + j];
    __syncthreads();
    float s = 0.f;
    for (int k = 0; k < 256; k++) s += in[k] * Wsr[(long long)k * 128 + j];
    float ss = wsum(s * s);
    if ((j & 63) == 0) red[j >> 6] = ss;
    __syncthreads();
    float nrm = sqrtf(red[0] + red[1]);
    sr[(long long)b * 128 + j] = s / (nrm + 1e-12f);
}

__global__ void k_rn(const float* __restrict__ emb, float* __restrict__ rn) {
    int row = blockIdx.x * 4 + (threadIdx.x >> 6);
    if (row >= V_) return;
    int l = threadIdx.x & 63;
    const float* p = emb + (long long)row * 128;
    float a = p[l], b = p[l + 64];
    float ss = wsum(a * a + b * b);
    if (l == 0) rn[row] = 1.f / (sqrtf(ss) + 1e-12f);
}

// ---------------- logits + fixed-shift log-softmax (|logit| <= 12) ----------------
// PASS0: rowsum[row] += sum_col exp(logit-12)  (no output write)
// PASS1: out = logit - 12 - log(rowsum[row])
template<int PASS>
__launch_bounds__(256)
__global__ void k_logits(const float* __restrict__ A, const float* __restrict__ Bt,
                         const float* __restrict__ rnv, float* __restrict__ rowsum,
                         float* __restrict__ C, int ncols) {
    __shared__ unsigned short As[128 * 40];
    __shared__ unsigned short Bs[128 * 40];
    __shared__ float sred[128];
    const int t = threadIdx.x;
    const int bm = blockIdx.x, bn = blockIdx.y;   // x-fastest: 8 row-blocks share emb tile
    const int lane = t & 63, wid = t >> 6;
    const int wr = wid >> 1, wc = wid & 1;
    const int lr = lane & 15, lh = lane >> 4;
    f32x4 acc[4][4] = {};
    for (int ks = 0; ks < 128; ks += 32) {
        #pragma unroll
        for (int i = 0; i < 4; i++) {
            int idx = i * 256 + t;
            int row = idx >> 3, kl = (idx & 7) * 4;
            float4 v = *(const float4*)&A[((long long)bm * 128 + row) * 128 + ks + kl];
            ushort4 bb; bb.x = f2b(v.x); bb.y = f2b(v.y); bb.z = f2b(v.z); bb.w = f2b(v.w);
            *(ushort4*)&As[row * 40 + kl] = bb;
        }
        #pragma unroll
        for (int i = 0; i < 4; i++) {
            int idx = i * 256 + t;
            int col = idx >> 3, kl = (idx & 7) * 4;
            long long gcol = (long long)bn * 128 + col;
            float4 v = make_float4(0.f, 0.f, 0.f, 0.f);
            if (gcol < ncols) v = *(const float4*)&Bt[gcol * 128 + ks + kl];
            ushort4 bb; bb.x = f2b(v.x); bb.y = f2b(v.y); bb.z = f2b(v.z); bb.w = f2b(v.w);
            *(ushort4*)&Bs[col * 40 + kl] = bb;
        }
        __syncthreads();
        bf16x8 af[4], bf[4];
        #pragma unroll
        for (int f = 0; f < 4; f++) {
            u16x8 ar = *(const u16x8*)&As[(wr * 64 + f * 16 + lr) * 40 + lh * 8];
            u16x8 br = *(const u16x8*)&Bs[(wc * 64 + f * 16 + lr) * 40 + lh * 8];
            af[f] = __builtin_bit_cast(bf16x8, ar);
            bf[f] = __builtin_bit_cast(bf16x8, br);
        }
        #pragma unroll
        for (int fr = 0; fr < 4; fr++)
            #pragma unroll
            for (int fc = 0; fc < 4; fc++)
                acc[fr][fc] = __builtin_amdgcn_mfma_f32_16x16x32_bf16(af[fr], bf[fc], acc[fr][fc], 0, 0, 0);
        __syncthreads();
    }
    if (PASS == 0) { if (t < 128) sred[t] = 0.f; }
    else           { if (t < 128) sred[t] = logf(rowsum[bm * 128 + t]); }
    __syncthreads();
    if (PASS == 0) {
        float pr[4][4] = {};
        #pragma unroll
        for (int fc = 0; fc < 4; fc++) {
            int col = bn * 128 + wc * 64 + fc * 16 + lr;
            if (col >= ncols) continue;
            float cs = rnv[col] * SCALE_;
            #pragma unroll
            for (int fr = 0; fr < 4; fr++)
                #pragma unroll
                for (int r = 0; r < 4; r++)
                    pr[fr][r] += expf(acc[fr][fc][r] * cs - SCALE_);
        }
        #pragma unroll
        for (int fr = 0; fr < 4; fr++)
            #pragma unroll
            for (int r = 0; r < 4; r++)
                atomicAdd(&sred[wr * 64 + fr * 16 + lh * 4 + r], pr[fr][r]);
        __syncthreads();
        if (t < 128) atomicAdd(&rowsum[bm * 128 + t], sred[t]);
    } else {
        #pragma unroll
        for (int fc = 0; fc < 4; fc++) {
            int col = bn * 128 + wc * 64 + fc * 16 + lr;
            if (col >= ncols) continue;
            float cs = rnv[col] * SCALE_;
            #pragma unroll
            for (int fr = 0; fr < 4; fr++) {
                int rowl = wr * 64 + fr * 16 + lh * 4;
                long long row0 = (long long)bm * 128 + rowl;
                #pragma unroll
                for (int r = 0; r < 4; r++)
                    C[(row0 + r) * ncols + col] = acc[fr][fc][r] * cs - SCALE_ - sred[rowl + r];
            }
        }
    }
}

// ================= host orchestration =================
extern "C" void kernel_launch(void* const* d_in, const int* in_sizes, int n_in,
                              void* d_out, int out_size, void* d_ws, size_t ws_size,
                              hipStream_t stream) {
    const int* iid   = (const int*)d_in[0];
    const int* esrc  = (const int*)d_in[1];
    const int* edst  = (const int*)d_in[2];
    const int* gid   = (const int*)d_in[3];
    const int* last  = (const int*)d_in[4];
    const float* ew  = (const float*)d_in[5];
    const float* et  = (const float*)d_in[6];
    const float* emb = (const float*)d_in[7];
    const float* W1  = (const float*)d_in[8];
    const float* W2  = (const float*)d_in[9];
    const float* wih = (const float*)d_in[10];
    const float* whh = (const float*)d_in[11];
    const float* bih = (const float*)d_in[12];
    const float* bhh = (const float*)d_in[13];
    const float* Wxr = (const float*)d_in[14]; const float* bxr = (const float*)d_in[15];
    const float* Wxz = (const float*)d_in[16]; const float* bxz = (const float*)d_in[17];
    const float* Wxh = (const float*)d_in[18]; const float* bxh = (const float*)d_in[19];
    const float* Whr = (const float*)d_in[20]; const float* bhr = (const float*)d_in[21];
    const float* Whz = (const float*)d_in[22]; const float* bhz = (const float*)d_in[23];
    const float* Whh = (const float*)d_in[24]; const float* bhh2 = (const float*)d_in[25];
    const float* fcu = (const float*)d_in[26];
    const float* fvw = (const float*)d_in[27]; const float* fvbv = (const float*)d_in[28];
    const float* fce = (const float*)d_in[29];
    const float* fsr = (const float*)d_in[30];
    float* out = (float*)d_out;

    float* Wk = (float*)d_ws;
    auto S = [&](int i) { return Wk + (long long)i * NS_; };
    float* FEAT = S(0);
    float* MIN = S(1);  float* H   = S(1);
    float* MOUT = S(2); float* ACC = S(2);
    float* GIH = S(3);                      // N x 512 = slots [3,7); dead after gru
    float* AX = S(3);
    float* AH = S(4);
    float* RB = S(5);
    float* ZB = S(6);
    float* FU = S(3);
    float* small = Wk + 9 * NS_;
    float* evec = small;   small += N_;
    float* alpha = small;  small += N_;
    float* dtp = small;    small += 64;
    float* BM1 = small;    small += 128 * 512;
    float* BM2 = small;    small += 128 * 512;
    float* BM3 = small;    small += 128 * 512;
    float* b512 = small;   small += 512;
    float* fvb = small;    small += B_ * 128;
    float* srg = small;    small += B_ * 128;
    float* srb = small;    small += B_ * 128;
    float* rnv = small;    small += V_;
    float* rowsum = small; small += B_;

    k_dtmax<<<1, 256, 0, stream>>>(et, dtp);
    k_feat0<<<N_ / 4, 256, 0, stream>>>(emb, iid, FEAT);

    // ---- stage A: weighted neighbor agg + fused GI/GH GEMM + GRU ----
    k_aggA_g<<<B_, 256, 0, stream>>>(esrc, edst, ew, FEAT, MIN, MOUT);
    k_prec512<<<256, 256, 0, stream>>>(W1, wih, 0, BM1);
    k_prec512<<<256, 256, 0, stream>>>(W2, wih, 256, BM2);
    k_prec3<<<256, 256, 0, stream>>>(whh, BM3);
    k_bias512<<<2, 256, 0, stream>>>(bih, bhh, b512);
    k_mm<3, 0><<<dim3(4, N_ / 128), 256, 0, stream>>>(
        MIN, MOUT, FEAT, BM1, BM2, BM3, 512, b512, nullptr, GIH, 512, 512);
    k_gru2<<<N_ / 4, 256, 0, stream>>>(GIH, FEAT);

    // ---- stage B: RK4 ODE ----
    hipMemcpyAsync(H, FEAT, NS_ * 4, hipMemcpyDeviceToDevice, stream);

    // mode: 0 = agg(x) only (h==x), 1 = agg(x)+agg(h), 2 = agg(h) only (mask reused)
    auto fstep = [&](float tfac, int mode, float accw, float hfac, int first) {
        if (mode == 0)
            k_gagg2<0><<<B_, 256, 0, stream>>>(esrc, edst, et, dtp, tfac, FEAT, nullptr, AX, nullptr);
        else if (mode == 1)
            k_gagg2<0><<<B_, 256, 0, stream>>>(esrc, edst, et, dtp, tfac, FEAT, H, AX, AH);
        else
            k_gagg2<0><<<B_, 256, 0, stream>>>(esrc, edst, et, dtp, tfac, H, nullptr, AH, nullptr);
        const float* AHp = (mode == 0) ? AX : AH;
        k_mm<2, 1><<<dim3(1, N_ / 128), 256, 0, stream>>>(
            AX, AHp, nullptr, Wxr, Whr, nullptr, 128, bxr, bhr, RB, 128, 128);
        k_mm<2, 1><<<dim3(1, N_ / 128), 256, 0, stream>>>(
            AX, AHp, nullptr, Wxz, Whz, nullptr, 128, bxz, bhz, ZB, 128, 128);
        k_gagg2<1><<<B_, 256, 0, stream>>>(esrc, edst, et, dtp, tfac, RB, H, AH, nullptr);
        k_u_dhu<<<dim3(1, N_ / 128), 256, 0, stream>>>(
            AX, AH, Wxh, Whh, bxh, bhh2, ZB, FEAT, ACC, H, dtp, accw, hfac, first);
    };

    fstep(0.0f, 0, 1.f, 0.5f, 1);
    fstep(0.5f, 1, 2.f, 0.5f, 0);
    fstep(0.5f, 2, 2.f, 1.0f, 0);
    fstep(1.0f, 1, 1.f, 0.0f, 0);
    k_fin<<<N_ / 4, 256, 0, stream>>>(FEAT, ACC, dtp);

    // ---- readout ----
    k_mm<1, 0><<<dim3(1, N_ / 128), 256, 0, stream>>>(
        FEAT, nullptr, nullptr, fcu, nullptr, nullptr, 128, nullptr, nullptr, FU, 128, 128);
    k_fv<<<B_, 128, 0, stream>>>(FEAT, last, fvw, fvbv, fvb);
    k_e<<<N_ / 4, 256, 0, stream>>>(FU, fvb, gid, fce, evec);
    k_softg<<<B_, 64, 0, stream>>>(evec, alpha);
    k_srg<<<B_, 128, 0, stream>>>(FEAT, alpha, srg);
    k_sr<<<B_, 128, 0, stream>>>(FEAT, last, srg, fsr, srb);
    k_rn<<<(V_ + 3) / 4, 256, 0, stream>>>(emb, rnv);

    hipMemsetAsync(rowsum, 0, B_ * 4, stream);
    k_logits<0><<<dim3(B_ / 128, (V_ + 127) / 128), 256, 0, stream>>>(
        srb, emb, rnv, rowsum, nullptr, V_);
    k_logits<1><<<dim3(B_ / 128, (V_ + 127) / 128), 256, 0, stream>>>(
        srb, emb, rnv, rowsum, out, V_);
}

// Round 5
// 1177.495 us; speedup vs baseline: 1.3714x; 1.3714x over previous
//
#include <hip/hip_runtime.h>
#include <math.h>

constexpr int V_ = 50000, D_ = 128, B_ = 1024, P_ = 50;
constexpr int N_ = 51200, E_ = 51200;
constexpr long long NS_ = (long long)N_ * D_;   // elems of an NxD buffer
constexpr float SCALE_ = 12.0f;
constexpr int NBN_L = (V_ + 127) / 128;          // 391 logit col tiles

typedef unsigned short u16;
typedef __attribute__((ext_vector_type(8))) unsigned short u16x8;
typedef __attribute__((ext_vector_type(8))) __bf16 bf16x8;
typedef __attribute__((ext_vector_type(4))) float f32x4;

static __device__ __forceinline__ float wsum(float v) {
    #pragma unroll
    for (int o = 32; o; o >>= 1) v += __shfl_xor(v, o, 64);
    return v;
}
static __device__ __forceinline__ float wmax(float v) {
    #pragma unroll
    for (int o = 32; o; o >>= 1) v = fmaxf(v, __shfl_xor(v, o, 64));
    return v;
}
static __device__ __forceinline__ float sig(float x) { return 1.f / (1.f + expf(-x)); }
static __device__ __forceinline__ u16 f2b(float x) {
    unsigned u = __float_as_uint(x);
    u += 0x7fffu + ((u >> 16) & 1u);
    return (u16)(u >> 16);
}
static __device__ __forceinline__ float b2f(u16 u) {
    return __uint_as_float(((unsigned)u) << 16);
}

// ---------------- emb -> bf16 copy + rnv = 1/(||row||+1e-12) ----------------
__global__ void k_embcv(const float* __restrict__ emb, u16* __restrict__ embb,
                        float* __restrict__ rnv) {
    int row = blockIdx.x * 4 + (threadIdx.x >> 6);
    if (row >= V_) return;
    int l = threadIdx.x & 63;
    const float* p = emb + (long long)row * D_;
    float a = p[l], b = p[l + 64];
    float ss = wsum(a * a + b * b);
    if (l == 0) rnv[row] = 1.f / (sqrtf(ss) + 1e-12f);
    u16* q = embb + (long long)row * D_;
    q[l] = f2b(a); q[l + 64] = f2b(b);
}

// ---------------- dt = max(edge_t) ----------------
__global__ void k_dtmax(const float* __restrict__ et, float* __restrict__ dt) {
    __shared__ float s[256];
    float m = 0.f;
    for (int i = threadIdx.x; i < E_; i += 256) m = fmaxf(m, et[i]);
    s[threadIdx.x] = m; __syncthreads();
    for (int o = 128; o; o >>= 1) {
        if (threadIdx.x < o) s[threadIdx.x] = fmaxf(s[threadIdx.x], s[threadIdx.x + o]);
        __syncthreads();
    }
    if (threadIdx.x == 0) *dt = s[0];
}

// ---------------- feat = normalize(embedding[iid]) ----------------
__global__ void k_feat0(const u16* __restrict__ embb, const float* __restrict__ rnv,
                        const int* __restrict__ iid,
                        float* __restrict__ feat, u16* __restrict__ featb) {
    int row = blockIdx.x * 4 + (threadIdx.x >> 6);
    int l = threadIdx.x & 63;
    int id = iid[row];
    const u16* p = embb + (long long)id * D_;
    float s = rnv[id];
    float a = b2f(p[l]) * s, b = b2f(p[l + 64]) * s;
    float* q = feat + (long long)row * D_;
    q[l] = a; q[l + 64] = b;
    u16* qb = featb + (long long)row * D_;
    qb[l] = f2b(a); qb[l + 64] = f2b(b);
}

// ---------------- stage-A per-graph weighted aggregation ----------------
__global__ void k_aggA_g(const int* __restrict__ esrc, const int* __restrict__ edst,
                         const float* __restrict__ ew, const u16* __restrict__ featb,
                         u16* __restrict__ m_in, u16* __restrict__ m_out) {
    __shared__ float sfeat[P_ * D_];
    __shared__ float smin[P_ * D_];
    __shared__ float smout[P_ * D_];
    __shared__ int ses[P_], sed[P_];
    __shared__ float sw[P_], swin[P_], swout[P_];
    int g = blockIdx.x, t = threadIdx.x;
    int n0 = g * P_;
    long long base = (long long)n0 * D_;
    for (int i = t; i < P_ * D_; i += 256) {
        sfeat[i] = b2f(featb[base + i]);
        smin[i] = 0.f; smout[i] = 0.f;
    }
    if (t < P_) {
        int E0 = g * P_ + t;
        ses[t] = esrc[E0] - n0;
        sed[t] = edst[E0] - n0;
        sw[t] = ew[E0];
    }
    __syncthreads();
    int d = t & 127;
    for (int e = 0; e < P_; e++) {
        int ls = ses[e], ld = sed[e];
        float w = sw[e];
        if (t < 128) smin[ld * D_ + d] += sfeat[ls * D_ + d] * w;
        else         smout[ls * D_ + d] += sfeat[ld * D_ + d] * w;
    }
    if (t < P_) {
        float wi = 0.f, wo = 0.f;
        for (int e = 0; e < P_; e++) {
            if (sed[e] == t) wi += sw[e];
            if (ses[e] == t) wo += sw[e];
        }
        swin[t] = (wi > 0.f) ? 1.f / wi : 1.f;
        swout[t] = (wo > 0.f) ? 1.f / wo : 1.f;
    }
    __syncthreads();
    for (int i = t; i < P_ * D_; i += 256) {
        int n = i >> 7;
        m_in[base + i] = f2b(smin[i] * swin[n]);
        m_out[base + i] = f2b(smout[i] * swout[n]);
    }
}

// ---------------- per-graph GCN aggregation via LDS CSR gather ----------------
// MODE0: out1 = D(a1), out2 = D(a2) if a2;  MODE1: out1 = D(a1*a2)
template<int MODE>
__launch_bounds__(256)
__global__ void k_gagg2(const int* __restrict__ esrc, const int* __restrict__ edst,
                        const float* __restrict__ et, const float* __restrict__ dtp, float tfac,
                        const u16* __restrict__ a1, int s1,
                        const u16* __restrict__ a2, int s2,
                        u16* __restrict__ out1, u16* __restrict__ out2) {
    constexpr int NSV = (MODE == 0) ? 2 : 1;
    __shared__ float sv[NSV * P_ * D_];
    __shared__ int ses[P_], sed[P_];
    __shared__ float snrm[P_];
    __shared__ int sdeg[P_], soff[P_ + 1];
    __shared__ int snbr[2 * P_];
    int g = blockIdx.x, t = threadIdx.x;
    int n0 = g * P_;
    long long base = (long long)n0 * D_;
    float tv = tfac * dtp[0];
    if (t < P_) {
        int E0 = g * P_ + t;
        int s = esrc[E0], dd = edst[E0];
        bool ml = (s != dd) && (et[E0] <= tv);
        ses[t] = ml ? (s - n0) : -1;
        sed[t] = ml ? (dd - n0) : -1;
    }
    __syncthreads();
    if (t < P_) {
        int deg = 0;
        for (int e = 0; e < P_; e++) deg += (ses[e] == t) + (sed[e] == t);
        sdeg[t] = deg;
        snrm[t] = rsqrtf(fmaxf((float)deg, 1.f));
    }
    __syncthreads();
    if (t == 0) {
        int off = 0;
        for (int n = 0; n < P_; n++) { soff[n] = off; off += sdeg[n]; }
        soff[P_] = off;
    }
    __syncthreads();
    if (t < P_) {
        int c = soff[t];
        for (int e = 0; e < P_; e++) {
            if (ses[e] == t) snbr[c++] = sed[e];
            if (sed[e] == t) snbr[c++] = ses[e];
        }
    }
    float* sv1 = sv;
    float* sv2 = sv + (NSV - 1) * P_ * D_;
    for (int i = t; i < P_ * D_; i += 256) {
        int n = i >> 7, d = i & 127;
        if (MODE == 1) {
            sv1[i] = b2f(a1[(long long)(n0 + n) * s1 + d]) *
                     b2f(a2[(long long)(n0 + n) * s2 + d]) * snrm[n];
        } else {
            sv1[i] = a1 ? b2f(a1[(long long)(n0 + n) * s1 + d]) * snrm[n] : 0.f;
            if (a2) sv2[i] = b2f(a2[(long long)(n0 + n) * s2 + d]) * snrm[n];
        }
    }
    __syncthreads();
    int d = t & 127;
    int nlo = (t >> 7) * 25;
    bool two = (MODE == 0) && (a2 != nullptr);
    for (int n = nlo; n < nlo + 25; n++) {
        float s1a = 0.f, s2a = 0.f;
        int j0 = soff[n], j1 = soff[n + 1];
        for (int j = j0; j < j1; j++) {
            int nb = snbr[j];
            s1a += sv1[nb * D_ + d];
            if (two) s2a += sv2[nb * D_ + d];
        }
        float nr = snrm[n];
        long long o = base + (long long)n * D_ + d;
        out1[o] = f2b(s1a * nr);
        if (two) out2[o] = f2b(s2a * nr);
    }
}

// ---------------- weight-panel precompute (bf16, [col][K] layout) ----------------
__global__ void k_prec_ab(const float* __restrict__ W, const float* __restrict__ wih, int coff,
                          u16* __restrict__ Bt) {
    int idx = blockIdx.x * 256 + threadIdx.x;
    if (idx >= 512 * 128) return;
    int j = idx >> 7, k = idx & 127;
    float s = 0.f;
    if (j < 384) {
        const float* wr = W + (long long)k * 256;
        const float* ir = wih + (long long)j * 512 + coff;
        for (int c = 0; c < 256; c++) s += wr[c] * ir[c];
    }
    Bt[idx] = f2b(s);
}

__global__ void k_prec3t(const float* __restrict__ whh, u16* __restrict__ Bt) {
    int idx = blockIdx.x * 256 + threadIdx.x;
    if (idx >= 512 * 128) return;
    int j = idx >> 7, k = idx & 127;
    float v = 0.f;
    if (j < 256) v = whh[(long long)j * 128 + k];
    else if (j >= 384) v = whh[(long long)(j - 128) * 128 + k];
    Bt[idx] = f2b(v);
}

__global__ void k_bias512(const float* __restrict__ bih, const float* __restrict__ bhh,
                          float* __restrict__ b512) {
    int j = blockIdx.x * 256 + threadIdx.x;
    if (j >= 512) return;
    float v;
    if (j < 256) v = bih[j] + bhh[j];
    else if (j < 384) v = bih[j];
    else v = bhh[j - 128];
    b512[j] = v;
}

__global__ void k_prec_rz(const float* __restrict__ Wxr, const float* __restrict__ Wxz,
                          const float* __restrict__ Whr, const float* __restrict__ Whz,
                          const float* __restrict__ bxr, const float* __restrict__ bxz,
                          const float* __restrict__ bhr, const float* __restrict__ bhz,
                          u16* __restrict__ B1, u16* __restrict__ B2,
                          float* __restrict__ bias) {
    int idx = blockIdx.x * 256 + threadIdx.x;
    if (idx >= 256 * 128) return;
    int c = idx >> 7, k = idx & 127;
    float v1 = (c < 128) ? Wxr[(long long)k * 128 + c] : Wxz[(long long)k * 128 + (c - 128)];
    float v2 = (c < 128) ? Whr[(long long)k * 128 + c] : Whz[(long long)k * 128 + (c - 128)];
    B1[idx] = f2b(v1); B2[idx] = f2b(v2);
    if (k == 0) bias[c] = (c < 128) ? bxr[c] + bhr[c] : bxz[c - 128] + bhz[c - 128];
}

__global__ void k_prec_u(const float* __restrict__ Wxh, const float* __restrict__ Whh,
                         const float* __restrict__ bxh, const float* __restrict__ bhh2,
                         u16* __restrict__ B1, u16* __restrict__ B2,
                         float* __restrict__ bias) {
    int idx = blockIdx.x * 256 + threadIdx.x;
    if (idx >= 128 * 128) return;
    int c = idx >> 7, k = idx & 127;
    B1[idx] = f2b(Wxh[(long long)k * 128 + c]);
    B2[idx] = f2b(Whh[(long long)k * 128 + c]);
    if (k == 0) bias[c] = bxh[c] + bhh2[c];
}

__global__ void k_prec_fc(const float* __restrict__ fcu, u16* __restrict__ Bt) {
    int idx = blockIdx.x * 256 + threadIdx.x;
    if (idx >= 128 * 128) return;
    int c = idx >> 7, k = idx & 127;
    Bt[idx] = f2b(fcu[(long long)k * 128 + c]);
}

// ---------------- bf16 MFMA GEMM: C(bf16) = act(sum_s A_s @ B_s^T + bias) -----------
// A_s: [row][128] bf16; B_s: [col][128] bf16 (pre-transposed). grid: 1D, XCD-chunked.
template<int NSEG, int ACT>
__launch_bounds__(256)
__global__ void k_mm(const u16* __restrict__ A1, const u16* __restrict__ A2,
                     const u16* __restrict__ A3,
                     const u16* __restrict__ B1, const u16* __restrict__ B2,
                     const u16* __restrict__ B3,
                     const float* __restrict__ bias,
                     u16* __restrict__ C, int ldc, int nbn) {
    __shared__ u16 As[128 * 40];
    __shared__ u16 Bs[128 * 40];
    const int t = threadIdx.x;
    const int bid = blockIdx.x;
    const int xcd = bid & 7, idx = bid >> 3;
    const int nbm8 = gridDim.x / (8 * nbn);
    const int bm = xcd * nbm8 + idx / nbn;
    const int bn = idx % nbn;
    const int lane = t & 63, wid = t >> 6;
    const int wr = wid >> 1, wc = wid & 1;
    const int lr = lane & 15, lh = lane >> 4;
    f32x4 acc[4][4] = {};
    constexpr int KTOT = NSEG * 128;
    for (int ks = 0; ks < KTOT; ks += 32) {
        const u16* Ap = (NSEG == 1) ? A1 : (ks < 128 ? A1 : (ks < 256 ? A2 : A3));
        const u16* Bp = (NSEG == 1) ? B1 : (ks < 128 ? B1 : (ks < 256 ? B2 : B3));
        int kk = ks & 127;
        #pragma unroll
        for (int i = 0; i < 2; i++) {
            int id2 = i * 256 + t;
            int row = id2 >> 2, kl = (id2 & 3) * 8;
            u16x8 va = *(const u16x8*)&Ap[((long long)bm * 128 + row) * 128 + kk + kl];
            *(u16x8*)&As[row * 40 + kl] = va;
            u16x8 vb = *(const u16x8*)&Bp[((long long)bn * 128 + row) * 128 + kk + kl];
            *(u16x8*)&Bs[row * 40 + kl] = vb;
        }
        __syncthreads();
        bf16x8 af[4], bf[4];
        #pragma unroll
        for (int f = 0; f < 4; f++) {
            u16x8 ar = *(const u16x8*)&As[(wr * 64 + f * 16 + lr) * 40 + lh * 8];
            u16x8 br = *(const u16x8*)&Bs[(wc * 64 + f * 16 + lr) * 40 + lh * 8];
            af[f] = __builtin_bit_cast(bf16x8, ar);
            bf[f] = __builtin_bit_cast(bf16x8, br);
        }
        #pragma unroll
        for (int fr = 0; fr < 4; fr++)
            #pragma unroll
            for (int fc = 0; fc < 4; fc++)
                acc[fr][fc] = __builtin_amdgcn_mfma_f32_16x16x32_bf16(af[fr], bf[fc], acc[fr][fc], 0, 0, 0);
        __syncthreads();
    }
    #pragma unroll
    for (int fc = 0; fc < 4; fc++) {
        int col = bn * 128 + wc * 64 + fc * 16 + lr;
        float bb = bias ? bias[col] : 0.f;
        #pragma unroll
        for (int fr = 0; fr < 4; fr++) {
            int rowl = wr * 64 + fr * 16 + lh * 4;
            long long row0 = (long long)bm * 128 + rowl;
            #pragma unroll
            for (int r = 0; r < 4; r++) {
                float v = acc[fr][fc][r] + bb;
                if (ACT == 1) v = sig(v);
                else if (ACT == 2) v = tanhf(v);
                C[(row0 + r) * (long long)ldc + col] = f2b(v);
            }
        }
    }
}

// ---------------- u-GEMM fused with dh/acc/h update (K=256) ----------------
__launch_bounds__(256)
__global__ void k_u_dhu(const u16* __restrict__ A1, const u16* __restrict__ A2,
                        const u16* __restrict__ B1, const u16* __restrict__ B2,
                        const float* __restrict__ bias,
                        const u16* __restrict__ RZ, const u16* __restrict__ featb,
                        float* __restrict__ acc_g, u16* __restrict__ h_g,
                        const float* __restrict__ dtp, float accw, float hfac, int first) {
    __shared__ u16 As[128 * 40];
    __shared__ u16 Bs[128 * 40];
    __shared__ float ssq[128];
    const int t = threadIdx.x;
    const int bm = blockIdx.x;
    const int lane = t & 63, wid = t >> 6;
    const int wr = wid >> 1, wc = wid & 1;
    const int lr = lane & 15, lh = lane >> 4;
    f32x4 acc[4][4] = {};
    for (int ks = 0; ks < 256; ks += 32) {
        const u16* Ap = (ks < 128) ? A1 : A2;
        const u16* Bp = (ks < 128) ? B1 : B2;
        int kk = ks & 127;
        #pragma unroll
        for (int i = 0; i < 2; i++) {
            int id2 = i * 256 + t;
            int row = id2 >> 2, kl = (id2 & 3) * 8;
            u16x8 va = *(const u16x8*)&Ap[((long long)bm * 128 + row) * 128 + kk + kl];
            *(u16x8*)&As[row * 40 + kl] = va;
            u16x8 vb = *(const u16x8*)&Bp[(long long)row * 128 + kk + kl];
            *(u16x8*)&Bs[row * 40 + kl] = vb;
        }
        __syncthreads();
        bf16x8 af[4], bf[4];
        #pragma unroll
        for (int f = 0; f < 4; f++) {
            u16x8 ar = *(const u16x8*)&As[(wr * 64 + f * 16 + lr) * 40 + lh * 8];
            u16x8 br = *(const u16x8*)&Bs[(wc * 64 + f * 16 + lr) * 40 + lh * 8];
            af[f] = __builtin_bit_cast(bf16x8, ar);
            bf[f] = __builtin_bit_cast(bf16x8, br);
        }
        #pragma unroll
        for (int fr = 0; fr < 4; fr++)
            #pragma unroll
            for (int fc = 0; fc < 4; fc++)
                acc[fr][fc] = __builtin_amdgcn_mfma_f32_16x16x32_bf16(af[fr], bf[fc], acc[fr][fc], 0, 0, 0);
        __syncthreads();
    }
    if (t < 128) ssq[t] = 0.f;
    __syncthreads();
    float pr[4][4] = {};
    #pragma unroll
    for (int fc = 0; fc < 4; fc++) {
        int col = wc * 64 + fc * 16 + lr;
        float bb = bias[col];
        #pragma unroll
        for (int fr = 0; fr < 4; fr++) {
            int rowl = wr * 64 + fr * 16 + lh * 4;
            #pragma unroll
            for (int r = 0; r < 4; r++) {
                long long row = (long long)bm * 128 + rowl + r;
                float u = tanhf(acc[fr][fc][r] + bb);
                float z = b2f(RZ[row * 256 + 128 + col]);
                float hh = b2f(h_g[row * 128 + col]);
                float v = (1.f - z) * (u - hh);
                acc[fr][fc][r] = v;
                pr[fr][r] += v * v;
            }
        }
    }
    #pragma unroll
    for (int fr = 0; fr < 4; fr++)
        #pragma unroll
        for (int r = 0; r < 4; r++)
            atomicAdd(&ssq[wr * 64 + fr * 16 + lh * 4 + r], pr[fr][r]);
    __syncthreads();
    float dt = dtp[0];
    #pragma unroll
    for (int fr = 0; fr < 4; fr++) {
        int rowl0 = wr * 64 + fr * 16 + lh * 4;
        #pragma unroll
        for (int r = 0; r < 4; r++) {
            float s = 1.f / fmaxf(sqrtf(ssq[rowl0 + r]), 1e-12f);
            long long row = (long long)bm * 128 + rowl0 + r;
            #pragma unroll
            for (int fc = 0; fc < 4; fc++) {
                int col = wc * 64 + fc * 16 + lr;
                long long ix = row * 128 + col;
                float kv = acc[fr][fc][r] * s;
                float an = (first ? 0.f : acc_g[ix]) + accw * kv;
                acc_g[ix] = an;
                if (hfac != 0.f) h_g[ix] = f2b(b2f(featb[ix]) + hfac * dt * kv);
            }
        }
    }
}

// ---------------- GRU ([r|z|inn|hnn] x 128) + renorm ----------------
__global__ void k_gru2(const u16* __restrict__ gih, float* __restrict__ feat,
                       u16* __restrict__ featb) {
    int row = blockIdx.x * 4 + (threadIdx.x >> 6);
    int l = threadIdx.x & 63;
    const u16* g = gih + (long long)row * 512;
    float* fr = feat + (long long)row * 128;
    float nv[2]; float ss = 0.f;
    #pragma unroll
    for (int tq = 0; tq < 2; tq++) {
        int d = l + tq * 64;
        float r = sig(b2f(g[d]));
        float z = sig(b2f(g[128 + d]));
        float n = tanhf(b2f(g[256 + d]) + r * b2f(g[384 + d]));
        float fv = fr[d];
        nv[tq] = (1.f - z) * n + z * fv;
        ss += nv[tq] * nv[tq];
    }
    ss = wsum(ss);
    float s = 1.f / fmaxf(sqrtf(ss), 1e-12f);
    float a = nv[0] * s, b = nv[1] * s;
    fr[l] = a; fr[l + 64] = b;
    u16* fb = featb + (long long)row * 128;
    fb[l] = f2b(a); fb[l + 64] = f2b(b);
}

__global__ void k_fin(float* __restrict__ feat, const float* __restrict__ acc,
                      const float* __restrict__ dtp, u16* __restrict__ featb) {
    int row = blockIdx.x * 4 + (threadIdx.x >> 6);
    int l = threadIdx.x & 63;
    long long base = (long long)row * 128;
    float dt6 = (*dtp) / 6.f;
    float v0 = feat[base + l] + dt6 * acc[base + l];
    float v1 = feat[base + l + 64] + dt6 * acc[base + l + 64];
    float ss = wsum(v0 * v0 + v1 * v1);
    float s = 1.f / sqrtf(ss);
    v0 *= s; v1 *= s;
    feat[base + l] = v0; feat[base + l + 64] = v1;
    featb[base + l] = f2b(v0); featb[base + l + 64] = f2b(v1);
}

// ---------------- readout ----------------
__global__ void k_fv(const float* __restrict__ feat, const int* __restrict__ last,
                     const float* __restrict__ Wv, const float* __restrict__ bv,
                     float* __restrict__ fv) {
    __shared__ float fr[128];
    int b = blockIdx.x; int j = threadIdx.x;
    fr[j] = feat[(long long)last[b] * 128 + j];
    __syncthreads();
    float s = bv[j];
    for (int k = 0; k < 128; k++) s += fr[k] * Wv[(long long)k * 128 + j];
    fv[(long long)b * 128 + j] = s;
}

__global__ void k_e(const u16* __restrict__ fu, const float* __restrict__ fv,
                    const int* __restrict__ gid, const float* __restrict__ fce,
                    float* __restrict__ e) {
    int row = blockIdx.x * 4 + (threadIdx.x >> 6);
    int l = threadIdx.x & 63;
    int g = gid[row];
    float s = 0.f;
    #pragma unroll
    for (int tq = 0; tq < 2; tq++) {
        int d = l + tq * 64;
        float x = b2f(fu[(long long)row * 128 + d]) + fv[(long long)g * 128 + d];
        s += sig(x) * fce[d];
    }
    s = wsum(s);
    if (l == 0) e[row] = s;
}

__global__ void k_softg(const float* __restrict__ e, float* __restrict__ alpha) {
    int b = blockIdx.x; int l = threadIdx.x;
    float v = (l < P_) ? e[b * P_ + l] : -1e30f;
    float m = wmax(v);
    float ex = (l < P_) ? expf(v - m) : 0.f;
    float s = wsum(ex);
    if (l < P_) alpha[b * P_ + l] = ex / s;
}

__global__ void k_srg(const u16* __restrict__ featb, const float* __restrict__ alpha,
                      float* __restrict__ srg) {
    int b = blockIdx.x; int d = threadIdx.x;
    float s = 0.f;
    for (int p = 0; p < P_; p++)
        s += b2f(featb[(long long)(b * P_ + p) * 128 + d]) * alpha[b * P_ + p];
    srg[(long long)b * 128 + d] = s;
}

__global__ void k_sr(const float* __restrict__ feat, const int* __restrict__ last,
                     const float* __restrict__ srg, const float* __restrict__ Wsr,
                     u16* __restrict__ srb) {
    __shared__ float in[256];
    __shared__ float red[2];
    int b = blockIdx.x; int j = threadIdx.x;
    in[j] = feat[(long long)last[b] * 128 + j];
    in[128 + j] = srg[(long long)b * 128 + j];
    __syncthreads();
    float s = 0.f;
    for (int k = 0; k < 256; k++) s += in[k] * Wsr[(long long)k * 128 + j];
    float ss = wsum(s * s);
    if ((j & 63) == 0) red[j >> 6] = ss;
    __syncthreads();
    float nrm = sqrtf(red[0] + red[1]);
    srb[(long long)b * 128 + j] = f2b(s / (nrm + 1e-12f));
}

// ---------------- logits + fixed-shift log-softmax (|logit| <= 12) ----------------
template<int PASS>
__launch_bounds__(256)
__global__ void k_logits(const u16* __restrict__ A, const u16* __restrict__ Bt,
                         const float* __restrict__ rnv, float* __restrict__ rowsum,
                         float* __restrict__ C) {
    __shared__ u16 As[128 * 40];
    __shared__ u16 Bs[128 * 40];
    __shared__ float sred[128];
    const int t = threadIdx.x;
    const int bid = blockIdx.x;
    const int xcd = bid & 7, idx = bid >> 3;
    const int bm = idx & 7, bnl = idx >> 3;
    const int bn = xcd * 49 + bnl;
    if (bn >= NBN_L) return;
    const int lane = t & 63, wid = t >> 6;
    const int wr = wid >> 1, wc = wid & 1;
    const int lr = lane & 15, lh = lane >> 4;
    f32x4 acc[4][4] = {};
    for (int ks = 0; ks < 128; ks += 32) {
        #pragma unroll
        for (int i = 0; i < 2; i++) {
            int id2 = i * 256 + t;
            int row = id2 >> 2, kl = (id2 & 3) * 8;
            u16x8 va = *(const u16x8*)&A[((long long)bm * 128 + row) * 128 + ks + kl];
            *(u16x8*)&As[row * 40 + kl] = va;
            long long gcol = (long long)bn * 128 + row;
            u16x8 vb;
            if (gcol < V_) vb = *(const u16x8*)&Bt[gcol * 128 + ks + kl];
            else vb = u16x8{0, 0, 0, 0, 0, 0, 0, 0};
            *(u16x8*)&Bs[row * 40 + kl] = vb;
        }
        __syncthreads();
        bf16x8 af[4], bf[4];
        #pragma unroll
        for (int f = 0; f < 4; f++) {
            u16x8 ar = *(const u16x8*)&As[(wr * 64 + f * 16 + lr) * 40 + lh * 8];
            u16x8 br = *(const u16x8*)&Bs[(wc * 64 + f * 16 + lr) * 40 + lh * 8];
            af[f] = __builtin_bit_cast(bf16x8, ar);
            bf[f] = __builtin_bit_cast(bf16x8, br);
        }
        #pragma unroll
        for (int fr = 0; fr < 4; fr++)
            #pragma unroll
            for (int fc = 0; fc < 4; fc++)
                acc[fr][fc] = __builtin_amdgcn_mfma_f32_16x16x32_bf16(af[fr], bf[fc], acc[fr][fc], 0, 0, 0);
        __syncthreads();
    }
    if (PASS == 0) { if (t < 128) sred[t] = 0.f; }
    else           { if (t < 128) sred[t] = logf(rowsum[bm * 128 + t]); }
    __syncthreads();
    if (PASS == 0) {
        float pr[4][4] = {};
        #pragma unroll
        for (int fc = 0; fc < 4; fc++) {
            int col = bn * 128 + wc * 64 + fc * 16 + lr;
            if (col >= V_) continue;
            float cs = rnv[col] * SCALE_;
            #pragma unroll
            for (int fr = 0; fr < 4; fr++)
                #pragma unroll
                for (int r = 0; r < 4; r++)
                    pr[fr][r] += expf(acc[fr][fc][r] * cs - SCALE_);
        }
        #pragma unroll
        for (int fr = 0; fr < 4; fr++)
            #pragma unroll
            for (int r = 0; r < 4; r++)
                atomicAdd(&sred[wr * 64 + fr * 16 + lh * 4 + r], pr[fr][r]);
        __syncthreads();
        if (t < 128) atomicAdd(&rowsum[bm * 128 + t], sred[t]);
    } else {
        #pragma unroll
        for (int fc = 0; fc < 4; fc++) {
            int col = bn * 128 + wc * 64 + fc * 16 + lr;
            if (col >= V_) continue;
            float cs = rnv[col] * SCALE_;
            #pragma unroll
            for (int fr = 0; fr < 4; fr++) {
                int rowl = wr * 64 + fr * 16 + lh * 4;
                long long row0 = (long long)bm * 128 + rowl;
                #pragma unroll
                for (int r = 0; r < 4; r++)
                    C[(row0 + r) * (long long)V_ + col] = acc[fr][fc][r] * cs - SCALE_ - sred[rowl + r];
            }
        }
    }
}

// ================= host orchestration =================
extern "C" void kernel_launch(void* const* d_in, const int* in_sizes, int n_in,
                              void* d_out, int out_size, void* d_ws, size_t ws_size,
                              hipStream_t stream) {
    const int* iid   = (const int*)d_in[0];
    const int* esrc  = (const int*)d_in[1];
    const int* edst  = (const int*)d_in[2];
    const int* gid   = (const int*)d_in[3];
    const int* last  = (const int*)d_in[4];
    const float* ew  = (const float*)d_in[5];
    const float* et  = (const float*)d_in[6];
    const float* emb = (const float*)d_in[7];
    const float* W1  = (const float*)d_in[8];
    const float* W2  = (const float*)d_in[9];
    const float* wih = (const float*)d_in[10];
    const float* whh = (const float*)d_in[11];
    const float* bih = (const float*)d_in[12];
    const float* bhh = (const float*)d_in[13];
    const float* Wxr = (const float*)d_in[14]; const float* bxr = (const float*)d_in[15];
    const float* Wxz = (const float*)d_in[16]; const float* bxz = (const float*)d_in[17];
    const float* Wxh = (const float*)d_in[18]; const float* bxh = (const float*)d_in[19];
    const float* Whr = (const float*)d_in[20]; const float* bhr = (const float*)d_in[21];
    const float* Whz = (const float*)d_in[22]; const float* bhz = (const float*)d_in[23];
    const float* Whh = (const float*)d_in[24]; const float* bhh2 = (const float*)d_in[25];
    const float* fcu = (const float*)d_in[26];
    const float* fvw = (const float*)d_in[27]; const float* fvbv = (const float*)d_in[28];
    const float* fce = (const float*)d_in[29];
    const float* fsr = (const float*)d_in[30];
    float* out = (float*)d_out;

    // ---- workspace layout (bytes) ----
    char* w = (char*)d_ws;
    auto alloc = [&](size_t bytes) { char* p = w; w += (bytes + 255) & ~(size_t)255; return p; };
    float* FEAT  = (float*)alloc(NS_ * 4);
    float* ACC   = (float*)alloc(NS_ * 4);
    u16* FEATb   = (u16*)alloc(NS_ * 2);
    u16* Hb      = (u16*)alloc(NS_ * 2);
    u16* MINb    = (u16*)alloc(NS_ * 2);
    u16* MOUTb   = (u16*)alloc(NS_ * 2);
    u16* GIHb    = (u16*)alloc(NS_ * 8);    // N x 512
    u16* AXb     = GIHb;                     // aliases (GIH dead after gru)
    u16* AHb     = GIHb + NS_;
    u16* RZb     = GIHb + 2 * NS_;           // N x 256
    u16* FUb     = MINb;                     // MINb dead after GIH gemm
    u16* embb    = (u16*)alloc((long long)V_ * 128 * 2);
    u16* srb     = (u16*)alloc(B_ * 128 * 2);
    u16* BM1t    = (u16*)alloc(512 * 128 * 2);
    u16* BM2t    = (u16*)alloc(512 * 128 * 2);
    u16* BM3t    = (u16*)alloc(512 * 128 * 2);
    u16* Brz1    = (u16*)alloc(256 * 128 * 2);
    u16* Brz2    = (u16*)alloc(256 * 128 * 2);
    u16* Bu1     = (u16*)alloc(128 * 128 * 2);
    u16* Bu2     = (u16*)alloc(128 * 128 * 2);
    u16* Bfc     = (u16*)alloc(128 * 128 * 2);
    float* b512  = (float*)alloc(512 * 4);
    float* brz   = (float*)alloc(256 * 4);
    float* bu    = (float*)alloc(128 * 4);
    float* dtp   = (float*)alloc(64 * 4);
    float* evec  = (float*)alloc(N_ * 4);
    float* alpha = (float*)alloc(N_ * 4);
    float* fvb   = (float*)alloc(B_ * 128 * 4);
    float* srg   = (float*)alloc(B_ * 128 * 4);
    float* rnv   = (float*)alloc((long long)V_ * 4);
    float* rowsum = (float*)alloc(B_ * 4);

    k_embcv<<<(V_ + 3) / 4, 256, 0, stream>>>(emb, embb, rnv);
    k_dtmax<<<1, 256, 0, stream>>>(et, dtp);
    k_feat0<<<N_ / 4, 256, 0, stream>>>(embb, rnv, iid, FEAT, FEATb);

    // ---- stage A ----
    k_aggA_g<<<B_, 256, 0, stream>>>(esrc, edst, ew, FEATb, MINb, MOUTb);
    k_prec_ab<<<256, 256, 0, stream>>>(W1, wih, 0, BM1t);
    k_prec_ab<<<256, 256, 0, stream>>>(W2, wih, 256, BM2t);
    k_prec3t<<<256, 256, 0, stream>>>(whh, BM3t);
    k_bias512<<<2, 256, 0, stream>>>(bih, bhh, b512);
    k_prec_rz<<<128, 256, 0, stream>>>(Wxr, Wxz, Whr, Whz, bxr, bxz, bhr, bhz, Brz1, Brz2, brz);
    k_prec_u<<<64, 256, 0, stream>>>(Wxh, Whh, bxh, bhh2, Bu1, Bu2, bu);
    k_prec_fc<<<64, 256, 0, stream>>>(fcu, Bfc);
    k_mm<3, 0><<<1600, 256, 0, stream>>>(MINb, MOUTb, FEATb, BM1t, BM2t, BM3t, b512, GIHb, 512, 4);
    k_gru2<<<N_ / 4, 256, 0, stream>>>(GIHb, FEAT, FEATb);

    // ---- stage B: RK4 ----
    hipMemcpyAsync(Hb, FEATb, NS_ * 2, hipMemcpyDeviceToDevice, stream);

    auto fstep = [&](float tfac, int mode, float accw, float hfac, int first) {
        if (mode == 0)
            k_gagg2<0><<<B_, 256, 0, stream>>>(esrc, edst, et, dtp, tfac, FEATb, 128, nullptr, 0, AXb, nullptr);
        else if (mode == 1)
            k_gagg2<0><<<B_, 256, 0, stream>>>(esrc, edst, et, dtp, tfac, FEATb, 128, Hb, 128, AXb, AHb);
        else
            k_gagg2<0><<<B_, 256, 0, stream>>>(esrc, edst, et, dtp, tfac, Hb, 128, nullptr, 0, AHb, nullptr);
        const u16* AHp = (mode == 0) ? AXb : AHb;
        k_mm<2, 1><<<800, 256, 0, stream>>>(AXb, AHp, nullptr, Brz1, Brz2, nullptr, brz, RZb, 256, 2);
        k_gagg2<1><<<B_, 256, 0, stream>>>(esrc, edst, et, dtp, tfac, RZb, 256, Hb, 128, AHb, nullptr);
        k_u_dhu<<<400, 256, 0, stream>>>(AXb, AHb, Bu1, Bu2, bu, RZb, FEATb, ACC, Hb, dtp, accw, hfac, first);
    };

    fstep(0.0f, 0, 1.f, 0.5f, 1);
    fstep(0.5f, 1, 2.f, 0.5f, 0);
    fstep(0.5f, 2, 2.f, 1.0f, 0);
    fstep(1.0f, 1, 1.f, 0.0f, 0);
    k_fin<<<N_ / 4, 256, 0, stream>>>(FEAT, ACC, dtp, FEATb);

    // ---- readout ----
    k_mm<1, 0><<<400, 256, 0, stream>>>(FEATb, nullptr, nullptr, Bfc, nullptr, nullptr,
                                        nullptr, FUb, 128, 1);
    k_fv<<<B_, 128, 0, stream>>>(FEAT, last, fvw, fvbv, fvb);
    k_e<<<N_ / 4, 256, 0, stream>>>(FUb, fvb, gid, fce, evec);
    k_softg<<<B_, 64, 0, stream>>>(evec, alpha);
    k_srg<<<B_, 128, 0, stream>>>(FEATb, alpha, srg);
    k_sr<<<B_, 128, 0, stream>>>(FEAT, last, srg, fsr, srb);

    hipMemsetAsync(rowsum, 0, B_ * 4, stream);
    k_logits<0><<<3136, 256, 0, stream>>>(srb, embb, rnv, rowsum, nullptr);
    k_logits<1><<<3136, 256, 0, stream>>>(srb, embb, rnv, rowsum, out);
}

// Round 7
// 1087.627 us; speedup vs baseline: 1.4847x; 1.0826x over previous
//
#include <hip/hip_runtime.h>
#include <math.h>

constexpr int V_ = 50000, D_ = 128, B_ = 1024, P_ = 50;
constexpr int N_ = 51200, E_ = 51200;
constexpr long long NS_ = (long long)N_ * D_;
constexpr float SCALE_ = 12.0f;
constexpr int NBN_L = (V_ + 127) / 128;   // 391
constexpr int NBN_P = 392;                // padded row stride for partials

typedef unsigned short u16;
typedef __attribute__((ext_vector_type(8))) unsigned short u16x8;
typedef __attribute__((ext_vector_type(8))) __bf16 bf16x8;
typedef __attribute__((ext_vector_type(4))) float f32x4;

static __device__ __forceinline__ float wsum(float v) {
    #pragma unroll
    for (int o = 32; o; o >>= 1) v += __shfl_xor(v, o, 64);
    return v;
}
static __device__ __forceinline__ float wmax(float v) {
    #pragma unroll
    for (int o = 32; o; o >>= 1) v = fmaxf(v, __shfl_xor(v, o, 64));
    return v;
}
static __device__ __forceinline__ float sig(float x) { return 1.f / (1.f + expf(-x)); }
static __device__ __forceinline__ u16 f2b(float x) {
    unsigned u = __float_as_uint(x);
    u += 0x7fffu + ((u >> 16) & 1u);
    return (u16)(u >> 16);
}
static __device__ __forceinline__ float b2f(u16 u) {
    return __uint_as_float(((unsigned)u) << 16);
}

// ---------------- emb -> bf16 + rnv ----------------
__global__ void k_embcv(const float* __restrict__ emb, u16* __restrict__ embb,
                        float* __restrict__ rnv) {
    int row = blockIdx.x * 4 + (threadIdx.x >> 6);
    if (row >= V_) return;
    int l = threadIdx.x & 63;
    const float* p = emb + (long long)row * D_;
    float a = p[l], b = p[l + 64];
    float ss = wsum(a * a + b * b);
    if (l == 0) rnv[row] = 1.f / (sqrtf(ss) + 1e-12f);
    u16* q = embb + (long long)row * D_;
    q[l] = f2b(a); q[l + 64] = f2b(b);
}

// ---------------- dt = max(edge_t) ----------------
__global__ void k_dtmax(const float* __restrict__ et, float* __restrict__ dt) {
    __shared__ float s[1024];
    float m = 0.f;
    for (int i = threadIdx.x; i < E_; i += 1024) m = fmaxf(m, et[i]);
    s[threadIdx.x] = m; __syncthreads();
    for (int o = 512; o; o >>= 1) {
        if (threadIdx.x < o) s[threadIdx.x] = fmaxf(s[threadIdx.x], s[threadIdx.x + o]);
        __syncthreads();
    }
    if (threadIdx.x == 0) *dt = s[0];
}

// ---------------- feat0 ----------------
__global__ void k_feat0(const u16* __restrict__ embb, const float* __restrict__ rnv,
                        const int* __restrict__ iid,
                        float* __restrict__ feat, u16* __restrict__ featb) {
    int row = blockIdx.x * 4 + (threadIdx.x >> 6);
    int l = threadIdx.x & 63;
    int id = iid[row];
    const u16* p = embb + (long long)id * D_;
    float s = rnv[id];
    float a = b2f(p[l]) * s, b = b2f(p[l + 64]) * s;
    float* q = feat + (long long)row * D_;
    q[l] = a; q[l + 64] = b;
    u16* qb = featb + (long long)row * D_;
    qb[l] = f2b(a); qb[l + 64] = f2b(b);
}

// ---------------- stage-A per-graph weighted aggregation ----------------
__global__ void k_aggA_g(const int* __restrict__ esrc, const int* __restrict__ edst,
                         const float* __restrict__ ew, const u16* __restrict__ featb,
                         u16* __restrict__ m_in, u16* __restrict__ m_out) {
    __shared__ float sfeat[P_ * D_];
    __shared__ float smin[P_ * D_];
    __shared__ float smout[P_ * D_];
    __shared__ int ses[P_], sed[P_];
    __shared__ float sw[P_], swin[P_], swout[P_];
    int g = blockIdx.x, t = threadIdx.x;
    int n0 = g * P_;
    long long base = (long long)n0 * D_;
    for (int i = t; i < P_ * D_; i += 256) {
        sfeat[i] = b2f(featb[base + i]);
        smin[i] = 0.f; smout[i] = 0.f;
    }
    if (t < P_) {
        int E0 = g * P_ + t;
        ses[t] = esrc[E0] - n0;
        sed[t] = edst[E0] - n0;
        sw[t] = ew[E0];
    }
    __syncthreads();
    int d = t & 127;
    for (int e = 0; e < P_; e++) {
        int ls = ses[e], ld = sed[e];
        float w = sw[e];
        if (t < 128) smin[ld * D_ + d] += sfeat[ls * D_ + d] * w;
        else         smout[ls * D_ + d] += sfeat[ld * D_ + d] * w;
    }
    if (t < P_) {
        float wi = 0.f, wo = 0.f;
        for (int e = 0; e < P_; e++) {
            if (sed[e] == t) wi += sw[e];
            if (ses[e] == t) wo += sw[e];
        }
        swin[t] = (wi > 0.f) ? 1.f / wi : 1.f;
        swout[t] = (wo > 0.f) ? 1.f / wo : 1.f;
    }
    __syncthreads();
    for (int i = t; i < P_ * D_; i += 256) {
        int n = i >> 7;
        m_in[base + i] = f2b(smin[i] * swin[n]);
        m_out[base + i] = f2b(smout[i] * swout[n]);
    }
}

// ---------------- per-graph GCN aggregation (LDS CSR gather) ----------------
template<int MODE>
__launch_bounds__(256)
__global__ void k_gagg2(const int* __restrict__ esrc, const int* __restrict__ edst,
                        const float* __restrict__ et, const float* __restrict__ dtp, float tfac,
                        const u16* __restrict__ a1, int s1,
                        const u16* __restrict__ a2, int s2,
                        u16* __restrict__ out1, u16* __restrict__ out2) {
    constexpr int NSV = (MODE == 0) ? 2 : 1;
    __shared__ float sv[NSV * P_ * D_];
    __shared__ int ses[P_], sed[P_];
    __shared__ float snrm[P_];
    __shared__ int sdeg[P_], soff[P_ + 1];
    __shared__ int snbr[2 * P_];
    int g = blockIdx.x, t = threadIdx.x;
    int n0 = g * P_;
    long long base = (long long)n0 * D_;
    float tv = tfac * dtp[0];
    if (t < P_) {
        int E0 = g * P_ + t;
        int s = esrc[E0], dd = edst[E0];
        bool ml = (s != dd) && (et[E0] <= tv);
        ses[t] = ml ? (s - n0) : -1;
        sed[t] = ml ? (dd - n0) : -1;
    }
    __syncthreads();
    if (t < P_) {
        int deg = 0;
        for (int e = 0; e < P_; e++) deg += (ses[e] == t) + (sed[e] == t);
        sdeg[t] = deg;
        snrm[t] = rsqrtf(fmaxf((float)deg, 1.f));
    }
    __syncthreads();
    if (t == 0) {
        int off = 0;
        for (int n = 0; n < P_; n++) { soff[n] = off; off += sdeg[n]; }
        soff[P_] = off;
    }
    __syncthreads();
    if (t < P_) {
        int c = soff[t];
        for (int e = 0; e < P_; e++) {
            if (ses[e] == t) snbr[c++] = sed[e];
            if (sed[e] == t) snbr[c++] = ses[e];
        }
    }
    float* sv1 = sv;
    float* sv2 = sv + (NSV - 1) * P_ * D_;
    for (int i = t; i < P_ * D_; i += 256) {
        int n = i >> 7, d = i & 127;
        if (MODE == 1) {
            sv1[i] = b2f(a1[(long long)(n0 + n) * s1 + d]) *
                     b2f(a2[(long long)(n0 + n) * s2 + d]) * snrm[n];
        } else {
            sv1[i] = a1 ? b2f(a1[(long long)(n0 + n) * s1 + d]) * snrm[n] : 0.f;
            if (a2) sv2[i] = b2f(a2[(long long)(n0 + n) * s2 + d]) * snrm[n];
        }
    }
    __syncthreads();
    int d = t & 127;
    int nlo = (t >> 7) * 25;
    bool two = (MODE == 0) && (a2 != nullptr);
    for (int n = nlo; n < nlo + 25; n++) {
        float s1a = 0.f, s2a = 0.f;
        int j0 = soff[n], j1 = soff[n + 1];
        for (int j = j0; j < j1; j++) {
            int nb = snbr[j];
            s1a += sv1[nb * D_ + d];
            if (two) s2a += sv2[nb * D_ + d];
        }
        float nr = snrm[n];
        long long o = base + (long long)n * D_ + d;
        out1[o] = f2b(s1a * nr);
        if (two) out2[o] = f2b(s2a * nr);
    }
}

// ---------------- merged weight precompute ----------------
__global__ void k_prec_all(const float* __restrict__ W1, const float* __restrict__ W2,
                           const float* __restrict__ wih, const float* __restrict__ whh,
                           const float* __restrict__ bih, const float* __restrict__ bhh,
                           const float* __restrict__ Wxr, const float* __restrict__ Wxz,
                           const float* __restrict__ Whr, const float* __restrict__ Whz,
                           const float* __restrict__ bxr, const float* __restrict__ bxz,
                           const float* __restrict__ bhr, const float* __restrict__ bhz,
                           const float* __restrict__ Wxh, const float* __restrict__ Whh,
                           const float* __restrict__ bxh, const float* __restrict__ bhh2,
                           const float* __restrict__ fcu,
                           u16* __restrict__ BM1t, u16* __restrict__ BM2t, u16* __restrict__ BM3t,
                           u16* __restrict__ Brz1, u16* __restrict__ Brz2,
                           u16* __restrict__ Bu1, u16* __restrict__ Bu2, u16* __restrict__ Bfc,
                           float* __restrict__ b512, float* __restrict__ brz,
                           float* __restrict__ bu) {
    int blk = blockIdx.x, t = threadIdx.x;
    if (blk < 512) {  // BM1t / BM2t: folded W@wih panels
        const float* W = (blk < 256) ? W1 : W2;
        int coff = (blk < 256) ? 0 : 256;
        u16* Bt = (blk < 256) ? BM1t : BM2t;
        int idx = (blk & 255) * 256 + t;
        int j = idx >> 7, k = idx & 127;
        float s = 0.f;
        if (j < 384) {
            const float* wr = W + (long long)k * 256;
            const float* ir = wih + (long long)j * 512 + coff;
            for (int c = 0; c < 256; c++) s += wr[c] * ir[c];
        }
        Bt[idx] = f2b(s);
    } else if (blk < 768) {  // BM3t
        int idx = (blk - 512) * 256 + t;
        int j = idx >> 7, k = idx & 127;
        float v = 0.f;
        if (j < 256) v = whh[(long long)j * 128 + k];
        else if (j >= 384) v = whh[(long long)(j - 128) * 128 + k];
        BM3t[idx] = f2b(v);
    } else if (blk < 896) {  // rz panels
        int idx = (blk - 768) * 256 + t;
        int c = idx >> 7, k = idx & 127;
        float v1 = (c < 128) ? Wxr[(long long)k * 128 + c] : Wxz[(long long)k * 128 + (c - 128)];
        float v2 = (c < 128) ? Whr[(long long)k * 128 + c] : Whz[(long long)k * 128 + (c - 128)];
        Brz1[idx] = f2b(v1); Brz2[idx] = f2b(v2);
        if (k == 0) brz[c] = (c < 128) ? bxr[c] + bhr[c] : bxz[c - 128] + bhz[c - 128];
    } else if (blk < 960) {  // u panels
        int idx = (blk - 896) * 256 + t;
        int c = idx >> 7, k = idx & 127;
        Bu1[idx] = f2b(Wxh[(long long)k * 128 + c]);
        Bu2[idx] = f2b(Whh[(long long)k * 128 + c]);
        if (k == 0) bu[c] = bxh[c] + bhh2[c];
    } else if (blk < 1024) {  // fc panel
        int idx = (blk - 960) * 256 + t;
        int c = idx >> 7, k = idx & 127;
        Bfc[idx] = f2b(fcu[(long long)k * 128 + c]);
    } else {  // b512 (2 blocks)
        int j = (blk - 1024) * 256 + t;
        if (j < 512) {
            float v;
            if (j < 256) v = bih[j] + bhh[j];
            else if (j < 384) v = bih[j];
            else v = bhh[j - 128];
            b512[j] = v;
        }
    }
}

// ---------------- bf16 MFMA GEMM (both operands [row][128] / [col][128]) --------
template<int NSEG, int ACT>
__launch_bounds__(256)
__global__ void k_mm(const u16* __restrict__ A1, const u16* __restrict__ A2,
                     const u16* __restrict__ A3,
                     const u16* __restrict__ B1, const u16* __restrict__ B2,
                     const u16* __restrict__ B3,
                     const float* __restrict__ bias,
                     u16* __restrict__ C, int ldc, int nbn) {
    __shared__ u16 As[128 * 40];
    __shared__ u16 Bs[128 * 40];
    const int t = threadIdx.x;
    const int bid = blockIdx.x;
    const int xcd = bid & 7, idx = bid >> 3;
    const int nbm8 = gridDim.x / (8 * nbn);
    const int bm = xcd * nbm8 + idx / nbn;
    const int bn = idx % nbn;
    const int lane = t & 63, wid = t >> 6;
    const int wr = wid >> 1, wc = wid & 1;
    const int lr = lane & 15, lh = lane >> 4;
    f32x4 acc[4][4] = {};
    constexpr int KTOT = NSEG * 128;
    for (int ks = 0; ks < KTOT; ks += 32) {
        const u16* Ap = (NSEG == 1) ? A1 : (ks < 128 ? A1 : (ks < 256 ? A2 : A3));
        const u16* Bp = (NSEG == 1) ? B1 : (ks < 128 ? B1 : (ks < 256 ? B2 : B3));
        int kk = ks & 127;
        #pragma unroll
        for (int i = 0; i < 2; i++) {
            int id2 = i * 256 + t;
            int row = id2 >> 2, kl = (id2 & 3) * 8;
            u16x8 va = *(const u16x8*)&Ap[((long long)bm * 128 + row) * 128 + kk + kl];
            *(u16x8*)&As[row * 40 + kl] = va;
            u16x8 vb = *(const u16x8*)&Bp[((long long)bn * 128 + row) * 128 + kk + kl];
            *(u16x8*)&Bs[row * 40 + kl] = vb;
        }
        __syncthreads();
        bf16x8 af[4], bf[4];
        #pragma unroll
        for (int f = 0; f < 4; f++) {
            u16x8 ar = *(const u16x8*)&As[(wr * 64 + f * 16 + lr) * 40 + lh * 8];
            u16x8 br = *(const u16x8*)&Bs[(wc * 64 + f * 16 + lr) * 40 + lh * 8];
            af[f] = __builtin_bit_cast(bf16x8, ar);
            bf[f] = __builtin_bit_cast(bf16x8, br);
        }
        #pragma unroll
        for (int fr = 0; fr < 4; fr++)
            #pragma unroll
            for (int fc = 0; fc < 4; fc++)
                acc[fr][fc] = __builtin_amdgcn_mfma_f32_16x16x32_bf16(af[fr], bf[fc], acc[fr][fc], 0, 0, 0);
        __syncthreads();
    }
    #pragma unroll
    for (int fc = 0; fc < 4; fc++) {
        int col = bn * 128 + wc * 64 + fc * 16 + lr;
        float bb = bias ? bias[col] : 0.f;
        #pragma unroll
        for (int fr = 0; fr < 4; fr++) {
            int rowl = wr * 64 + fr * 16 + lh * 4;
            long long row0 = (long long)bm * 128 + rowl;
            #pragma unroll
            for (int r = 0; r < 4; r++) {
                float v = acc[fr][fc][r] + bb;
                if (ACT == 1) v = sig(v);
                else if (ACT == 2) v = tanhf(v);
                C[(row0 + r) * (long long)ldc + col] = f2b(v);
            }
        }
    }
}

// ---------------- u-GEMM fused with dh/acc/h update; FIN also folds k_fin ----------
// hprev: stage state h (read). hout: write target (Hb for stages, FEATb for FIN).
template<int FIN>
__launch_bounds__(256)
__global__ void k_u_dhu(const u16* __restrict__ A1, const u16* __restrict__ A2,
                        const u16* __restrict__ B1, const u16* __restrict__ B2,
                        const float* __restrict__ bias,
                        const u16* __restrict__ RZ, const u16* __restrict__ featb,
                        const float* __restrict__ feat32,
                        const u16* __restrict__ hprev,
                        float* __restrict__ acc_g, u16* __restrict__ hout,
                        const float* __restrict__ dtp, float accw, float hfac, int first) {
    __shared__ u16 As[128 * 40];
    __shared__ u16 Bs[128 * 40];
    __shared__ float ssq[128];
    __shared__ float ssq2[128];
    const int t = threadIdx.x;
    const int bm = blockIdx.x;
    const int lane = t & 63, wid = t >> 6;
    const int wr = wid >> 1, wc = wid & 1;
    const int lr = lane & 15, lh = lane >> 4;
    f32x4 acc[4][4] = {};
    for (int ks = 0; ks < 256; ks += 32) {
        const u16* Ap = (ks < 128) ? A1 : A2;
        const u16* Bp = (ks < 128) ? B1 : B2;
        int kk = ks & 127;
        #pragma unroll
        for (int i = 0; i < 2; i++) {
            int id2 = i * 256 + t;
            int row = id2 >> 2, kl = (id2 & 3) * 8;
            u16x8 va = *(const u16x8*)&Ap[((long long)bm * 128 + row) * 128 + kk + kl];
            *(u16x8*)&As[row * 40 + kl] = va;
            u16x8 vb = *(const u16x8*)&Bp[(long long)row * 128 + kk + kl];
            *(u16x8*)&Bs[row * 40 + kl] = vb;
        }
        __syncthreads();
        bf16x8 af[4], bf[4];
        #pragma unroll
        for (int f = 0; f < 4; f++) {
            u16x8 ar = *(const u16x8*)&As[(wr * 64 + f * 16 + lr) * 40 + lh * 8];
            u16x8 br = *(const u16x8*)&Bs[(wc * 64 + f * 16 + lr) * 40 + lh * 8];
            af[f] = __builtin_bit_cast(bf16x8, ar);
            bf[f] = __builtin_bit_cast(bf16x8, br);
        }
        #pragma unroll
        for (int fr = 0; fr < 4; fr++)
            #pragma unroll
            for (int fc = 0; fc < 4; fc++)
                acc[fr][fc] = __builtin_amdgcn_mfma_f32_16x16x32_bf16(af[fr], bf[fc], acc[fr][fc], 0, 0, 0);
        __syncthreads();
    }
    if (t < 128) { ssq[t] = 0.f; ssq2[t] = 0.f; }
    __syncthreads();
    float pr[4][4] = {};
    #pragma unroll
    for (int fc = 0; fc < 4; fc++) {
        int col = wc * 64 + fc * 16 + lr;
        float bb = bias[col];
        #pragma unroll
        for (int fr = 0; fr < 4; fr++) {
            int rowl = wr * 64 + fr * 16 + lh * 4;
            #pragma unroll
            for (int r = 0; r < 4; r++) {
                long long row = (long long)bm * 128 + rowl + r;
                float u = tanhf(acc[fr][fc][r] + bb);
                float z = b2f(RZ[row * 256 + 128 + col]);
                float hh = b2f(hprev[row * 128 + col]);
                float v = (1.f - z) * (u - hh);
                acc[fr][fc][r] = v;
                pr[fr][r] += v * v;
            }
        }
    }
    #pragma unroll
    for (int fr = 0; fr < 4; fr++)
        #pragma unroll
        for (int r = 0; r < 4; r++)
            atomicAdd(&ssq[wr * 64 + fr * 16 + lh * 4 + r], pr[fr][r]);
    __syncthreads();
    float dt = dtp[0];
    if (FIN) {
        float dt6 = dt / 6.f;
        float pr2[4][4] = {};
        #pragma unroll
        for (int fr = 0; fr < 4; fr++) {
            int rowl0 = wr * 64 + fr * 16 + lh * 4;
            #pragma unroll
            for (int r = 0; r < 4; r++) {
                float s = 1.f / fmaxf(sqrtf(ssq[rowl0 + r]), 1e-12f);
                long long row = (long long)bm * 128 + rowl0 + r;
                #pragma unroll
                for (int fc = 0; fc < 4; fc++) {
                    int col = wc * 64 + fc * 16 + lr;
                    long long ix = row * 128 + col;
                    float kv = acc[fr][fc][r] * s;
                    float an = acc_g[ix] + accw * kv;          // final RK4 acc
                    float fv2 = feat32[ix] + dt6 * an;
                    acc[fr][fc][r] = fv2;
                    pr2[fr][r] += fv2 * fv2;
                }
            }
        }
        #pragma unroll
        for (int fr = 0; fr < 4; fr++)
            #pragma unroll
            for (int r = 0; r < 4; r++)
                atomicAdd(&ssq2[wr * 64 + fr * 16 + lh * 4 + r], pr2[fr][r]);
        __syncthreads();
        #pragma unroll
        for (int fr = 0; fr < 4; fr++) {
            int rowl0 = wr * 64 + fr * 16 + lh * 4;
            #pragma unroll
            for (int r = 0; r < 4; r++) {
                float s2 = 1.f / sqrtf(ssq2[rowl0 + r]);
                long long row = (long long)bm * 128 + rowl0 + r;
                #pragma unroll
                for (int fc = 0; fc < 4; fc++) {
                    int col = wc * 64 + fc * 16 + lr;
                    hout[row * 128 + col] = f2b(acc[fr][fc][r] * s2);
                }
            }
        }
    } else {
        #pragma unroll
        for (int fr = 0; fr < 4; fr++) {
            int rowl0 = wr * 64 + fr * 16 + lh * 4;
            #pragma unroll
            for (int r = 0; r < 4; r++) {
                float s = 1.f / fmaxf(sqrtf(ssq[rowl0 + r]), 1e-12f);
                long long row = (long long)bm * 128 + rowl0 + r;
                #pragma unroll
                for (int fc = 0; fc < 4; fc++) {
                    int col = wc * 64 + fc * 16 + lr;
                    long long ix = row * 128 + col;
                    float kv = acc[fr][fc][r] * s;
                    float an = (first ? 0.f : acc_g[ix]) + accw * kv;
                    acc_g[ix] = an;
                    hout[ix] = f2b(b2f(featb[ix]) + hfac * dt * kv);
                }
            }
        }
    }
}

// ---------------- GRU + renorm (also seeds H = feat) ----------------
__global__ void k_gru2(const u16* __restrict__ gih, float* __restrict__ feat,
                       u16* __restrict__ featb, u16* __restrict__ hb) {
    int row = blockIdx.x * 4 + (threadIdx.x >> 6);
    int l = threadIdx.x & 63;
    const u16* g = gih + (long long)row * 512;
    float* fr = feat + (long long)row * 128;
    float nv[2]; float ss = 0.f;
    #pragma unroll
    for (int tq = 0; tq < 2; tq++) {
        int d = l + tq * 64;
        float r = sig(b2f(g[d]));
        float z = sig(b2f(g[128 + d]));
        float n = tanhf(b2f(g[256 + d]) + r * b2f(g[384 + d]));
        float fv = fr[d];
        nv[tq] = (1.f - z) * n + z * fv;
        ss += nv[tq] * nv[tq];
    }
    ss = wsum(ss);
    float s = 1.f / fmaxf(sqrtf(ss), 1e-12f);
    float a = nv[0] * s, b = nv[1] * s;
    fr[l] = a; fr[l + 64] = b;
    u16 ab = f2b(a), bb = f2b(b);
    u16* fb = featb + (long long)row * 128;
    fb[l] = ab; fb[l + 64] = bb;
    u16* hh = hb + (long long)row * 128;
    hh[l] = ab; hh[l + 64] = bb;
}

// ---------------- fused readout: fv + e + softmax + srg + sr ----------------
__launch_bounds__(256)
__global__ void k_readout(const u16* __restrict__ featb, const u16* __restrict__ FU,
                          const int* __restrict__ last,
                          const float* __restrict__ fvw, const float* __restrict__ fvbv,
                          const float* __restrict__ fce, const float* __restrict__ fsr,
                          u16* __restrict__ srb) {
    __shared__ float sfl[128], sfv[128], se[64], sal[64], sin2[256], red[2];
    int g = blockIdx.x, t = threadIdx.x;
    int n0 = g * P_;
    long long ln = last[g];
    if (t < 128) sfl[t] = b2f(featb[ln * 128 + t]);
    __syncthreads();
    if (t < 128) {
        float s = fvbv[t];
        for (int k = 0; k < 128; k++) s += sfl[k] * fvw[(long long)k * 128 + t];
        sfv[t] = s;
        sin2[t] = sfl[t];
    }
    __syncthreads();
    int wid = t >> 6, lane = t & 63;
    float fce0 = fce[lane], fce1 = fce[lane + 64];
    for (int p = wid; p < P_; p += 4) {
        const u16* fu = FU + (long long)(n0 + p) * 128;
        float x0 = b2f(fu[lane]) + sfv[lane];
        float x1 = b2f(fu[lane + 64]) + sfv[lane + 64];
        float s = sig(x0) * fce0 + sig(x1) * fce1;
        s = wsum(s);
        if (lane == 0) se[p] = s;
    }
    __syncthreads();
    if (t < 64) {
        float v = (t < P_) ? se[t] : -1e30f;
        float m = wmax(v);
        float ex = (t < P_) ? expf(v - m) : 0.f;
        float ss = wsum(ex);
        if (t < P_) sal[t] = ex / ss;
    }
    __syncthreads();
    if (t < 128) {
        float s = 0.f;
        for (int p = 0; p < P_; p++)
            s += b2f(featb[(long long)(n0 + p) * 128 + t]) * sal[p];
        sin2[128 + t] = s;
    }
    __syncthreads();
    if (t < 128) {
        float s = 0.f;
        for (int k = 0; k < 256; k++) s += sin2[k] * fsr[(long long)k * 128 + t];
        float ss = wsum(s * s);
        if (lane == 0) red[t >> 6] = ss;
        __syncthreads();
        float nrm = sqrtf(red[0] + red[1]);
        srb[(long long)g * 128 + t] = f2b(s / (nrm + 1e-12f));
    } else {
        __syncthreads();
    }
}

// ---------------- logits + fixed-shift log-softmax (|logit| <= 12) ----------------
// PASS0: partial exp-sums -> rowsumP[row][bn] (no atomics). PASS1: out = logit-12-logZ.
template<int PASS>
__launch_bounds__(256)
__global__ void k_logits(const u16* __restrict__ A, const u16* __restrict__ Bt,
                         const float* __restrict__ rnv, float* __restrict__ rowsumP,
                         const float* __restrict__ logz, float* __restrict__ C) {
    __shared__ u16 As[128 * 40];
    __shared__ u16 Bs[128 * 40];
    __shared__ float sred[128];
    const int t = threadIdx.x;
    const int bid = blockIdx.x;
    const int xcd = bid & 7, idx = bid >> 3;
    const int bm = idx & 7, bnl = idx >> 3;
    const int bn = xcd * 49 + bnl;
    if (bn >= NBN_L) return;
    const int lane = t & 63, wid = t >> 6;
    const int wr = wid >> 1, wc = wid & 1;
    const int lr = lane & 15, lh = lane >> 4;
    f32x4 acc[4][4] = {};
    for (int ks = 0; ks < 128; ks += 32) {
        #pragma unroll
        for (int i = 0; i < 2; i++) {
            int id2 = i * 256 + t;
            int row = id2 >> 2, kl = (id2 & 3) * 8;
            u16x8 va = *(const u16x8*)&A[((long long)bm * 128 + row) * 128 + ks + kl];
            *(u16x8*)&As[row * 40 + kl] = va;
            long long gcol = (long long)bn * 128 + row;
            u16x8 vb;
            if (gcol < V_) vb = *(const u16x8*)&Bt[gcol * 128 + ks + kl];
            else vb = u16x8{0, 0, 0, 0, 0, 0, 0, 0};
            *(u16x8*)&Bs[row * 40 + kl] = vb;
        }
        __syncthreads();
        bf16x8 af[4], bf[4];
        #pragma unroll
        for (int f = 0; f < 4; f++) {
            u16x8 ar = *(const u16x8*)&As[(wr * 64 + f * 16 + lr) * 40 + lh * 8];
            u16x8 br = *(const u16x8*)&Bs[(wc * 64 + f * 16 + lr) * 40 + lh * 8];
            af[f] = __builtin_bit_cast(bf16x8, ar);
            bf[f] = __builtin_bit_cast(bf16x8, br);
        }
        #pragma unroll
        for (int fr = 0; fr < 4; fr++)
            #pragma unroll
            for (int fc = 0; fc < 4; fc++)
                acc[fr][fc] = __builtin_amdgcn_mfma_f32_16x16x32_bf16(af[fr], bf[fc], acc[fr][fc], 0, 0, 0);
        __syncthreads();
    }
    if (PASS == 0) { if (t < 128) sred[t] = 0.f; }
    else           { if (t < 128) sred[t] = logz[bm * 128 + t]; }
    __syncthreads();
    if (PASS == 0) {
        float pr[4][4] = {};
        #pragma unroll
        for (int fc = 0; fc < 4; fc++) {
            int col = bn * 128 + wc * 64 + fc * 16 + lr;
            if (col >= V_) continue;
            float cs = rnv[col] * SCALE_;
            #pragma unroll
            for (int fr = 0; fr < 4; fr++)
                #pragma unroll
                for (int r = 0; r < 4; r++)
                    pr[fr][r] += expf(acc[fr][fc][r] * cs - SCALE_);
        }
        #pragma unroll
        for (int fr = 0; fr < 4; fr++)
            #pragma unroll
            for (int r = 0; r < 4; r++)
                atomicAdd(&sred[wr * 64 + fr * 16 + lh * 4 + r], pr[fr][r]);
        __syncthreads();
        if (t < 128) rowsumP[(long long)(bm * 128 + t) * NBN_P + bn] = sred[t];
    } else {
        #pragma unroll
        for (int fc = 0; fc < 4; fc++) {
            int col = bn * 128 + wc * 64 + fc * 16 + lr;
            if (col >= V_) continue;
            float cs = rnv[col] * SCALE_;
            #pragma unroll
            for (int fr = 0; fr < 4; fr++) {
                int rowl = wr * 64 + fr * 16 + lh * 4;
                long long row0 = (long long)bm * 128 + rowl;
                #pragma unroll
                for (int r = 0; r < 4; r++)
                    C[(row0 + r) * (long long)V_ + col] = acc[fr][fc][r] * cs - SCALE_ - sred[rowl + r];
            }
        }
    }
}

// reduce partials: logz[row] = log( sum_j rowsumP[row][j] )
__global__ void k_rsum(const float* __restrict__ rowsumP, float* __restrict__ logz) {
    int t = threadIdx.x;
    int row = blockIdx.x * 128 + (t >> 1);
    int half = t & 1;
    const float* p = rowsumP + (long long)row * NBN_P;
    float s = 0.f;
    int j0 = half ? 196 : 0, j1 = half ? NBN_L : 196;
    for (int j = j0; j < j1; j++) s += p[j];
    s += __shfl_xor(s, 1);
    if (!half) logz[row] = logf(s);
}

// ================= host orchestration =================
extern "C" void kernel_launch(void* const* d_in, const int* in_sizes, int n_in,
                              void* d_out, int out_size, void* d_ws, size_t ws_size,
                              hipStream_t stream) {
    const int* iid   = (const int*)d_in[0];
    const int* esrc  = (const int*)d_in[1];
    const int* edst  = (const int*)d_in[2];
    const int* last  = (const int*)d_in[4];
    const float* ew  = (const float*)d_in[5];
    const float* et  = (const float*)d_in[6];
    const float* emb = (const float*)d_in[7];
    const float* W1  = (const float*)d_in[8];
    const float* W2  = (const float*)d_in[9];
    const float* wih = (const float*)d_in[10];
    const float* whh = (const float*)d_in[11];
    const float* bih = (const float*)d_in[12];
    const float* bhh = (const float*)d_in[13];
    const float* Wxr = (const float*)d_in[14]; const float* bxr = (const float*)d_in[15];
    const float* Wxz = (const float*)d_in[16]; const float* bxz = (const float*)d_in[17];
    const float* Wxh = (const float*)d_in[18]; const float* bxh = (const float*)d_in[19];
    const float* Whr = (const float*)d_in[20]; const float* bhr = (const float*)d_in[21];
    const float* Whz = (const float*)d_in[22]; const float* bhz = (const float*)d_in[23];
    const float* Whh = (const float*)d_in[24]; const float* bhh2 = (const float*)d_in[25];
    const float* fcu = (const float*)d_in[26];
    const float* fvw = (const float*)d_in[27]; const float* fvbv = (const float*)d_in[28];
    const float* fce = (const float*)d_in[29];
    const float* fsr = (const float*)d_in[30];
    float* out = (float*)d_out;

    char* w = (char*)d_ws;
    auto alloc = [&](size_t bytes) { char* p = w; w += (bytes + 255) & ~(size_t)255; return p; };
    float* FEAT  = (float*)alloc(NS_ * 4);
    float* ACC   = (float*)alloc(NS_ * 4);
    u16* FEATb   = (u16*)alloc(NS_ * 2);
    u16* Hb      = (u16*)alloc(NS_ * 2);
    u16* MINb    = (u16*)alloc(NS_ * 2);
    u16* MOUTb   = (u16*)alloc(NS_ * 2);
    u16* GIHb    = (u16*)alloc(NS_ * 8);    // N x 512
    u16* AXb     = GIHb;
    u16* AHb     = GIHb + NS_;
    u16* RZb     = GIHb + 2 * NS_;          // N x 256
    u16* FUb     = MINb;                    // MINb dead after GIH gemm
    u16* embb    = (u16*)alloc((long long)V_ * 128 * 2);
    u16* srb     = (u16*)alloc(B_ * 128 * 2);
    u16* BM1t    = (u16*)alloc(512 * 128 * 2);
    u16* BM2t    = (u16*)alloc(512 * 128 * 2);
    u16* BM3t    = (u16*)alloc(512 * 128 * 2);
    u16* Brz1    = (u16*)alloc(256 * 128 * 2);
    u16* Brz2    = (u16*)alloc(256 * 128 * 2);
    u16* Bu1     = (u16*)alloc(128 * 128 * 2);
    u16* Bu2     = (u16*)alloc(128 * 128 * 2);
    u16* Bfc     = (u16*)alloc(128 * 128 * 2);
    float* b512  = (float*)alloc(512 * 4);
    float* brz   = (float*)alloc(256 * 4);
    float* bu    = (float*)alloc(128 * 4);
    float* dtp   = (float*)alloc(64 * 4);
    float* rnv   = (float*)alloc((long long)V_ * 4);
    float* rowsumP = (float*)alloc((long long)B_ * NBN_P * 4);
    float* logz  = (float*)alloc(B_ * 4);

    k_embcv<<<(V_ + 3) / 4, 256, 0, stream>>>(emb, embb, rnv);
    k_dtmax<<<1, 1024, 0, stream>>>(et, dtp);
    k_feat0<<<N_ / 4, 256, 0, stream>>>(embb, rnv, iid, FEAT, FEATb);

    // ---- stage A ----
    k_aggA_g<<<B_, 256, 0, stream>>>(esrc, edst, ew, FEATb, MINb, MOUTb);
    k_prec_all<<<1026, 256, 0, stream>>>(W1, W2, wih, whh, bih, bhh,
                                         Wxr, Wxz, Whr, Whz, bxr, bxz, bhr, bhz,
                                         Wxh, Whh, bxh, bhh2, fcu,
                                         BM1t, BM2t, BM3t, Brz1, Brz2, Bu1, Bu2, Bfc,
                                         b512, brz, bu);
    k_mm<3, 0><<<1600, 256, 0, stream>>>(MINb, MOUTb, FEATb, BM1t, BM2t, BM3t, b512, GIHb, 512, 4);
    k_gru2<<<N_ / 4, 256, 0, stream>>>(GIHb, FEAT, FEATb, Hb);

    // ---- stage B: RK4 ----
    auto fstep = [&](float tfac, int mode, float accw, float hfac, int first, int fin) {
        if (mode == 0)
            k_gagg2<0><<<B_, 256, 0, stream>>>(esrc, edst, et, dtp, tfac, FEATb, 128, nullptr, 0, AXb, nullptr);
        else if (mode == 1)
            k_gagg2<0><<<B_, 256, 0, stream>>>(esrc, edst, et, dtp, tfac, FEATb, 128, Hb, 128, AXb, AHb);
        else
            k_gagg2<0><<<B_, 256, 0, stream>>>(esrc, edst, et, dtp, tfac, Hb, 128, nullptr, 0, AHb, nullptr);
        const u16* AHp = (mode == 0) ? AXb : AHb;
        k_mm<2, 1><<<800, 256, 0, stream>>>(AXb, AHp, nullptr, Brz1, Brz2, nullptr, brz, RZb, 256, 2);
        k_gagg2<1><<<B_, 256, 0, stream>>>(esrc, edst, et, dtp, tfac, RZb, 256, Hb, 128, AHb, nullptr);
        if (fin)
            k_u_dhu<1><<<400, 256, 0, stream>>>(AXb, AHb, Bu1, Bu2, bu, RZb, FEATb, FEAT,
                                                Hb, ACC, FEATb, dtp, accw, hfac, first);
        else
            k_u_dhu<0><<<400, 256, 0, stream>>>(AXb, AHb, Bu1, Bu2, bu, RZb, FEATb, FEAT,
                                                Hb, ACC, Hb, dtp, accw, hfac, first);
    };

    fstep(0.0f, 0, 1.f, 0.5f, 1, 0);
    fstep(0.5f, 1, 2.f, 0.5f, 0, 0);
    fstep(0.5f, 2, 2.f, 1.0f, 0, 0);
    fstep(1.0f, 1, 1.f, 0.0f, 0, 1);   // fused k_fin: writes final normalized FEATb

    // ---- readout ----
    k_mm<1, 0><<<400, 256, 0, stream>>>(FEATb, nullptr, nullptr, Bfc, nullptr, nullptr,
                                        nullptr, FUb, 128, 1);
    k_readout<<<B_, 256, 0, stream>>>(FEATb, FUb, last, fvw, fvbv, fce, fsr, srb);

    k_logits<0><<<3136, 256, 0, stream>>>(srb, embb, rnv, rowsumP, nullptr, nullptr);
    k_rsum<<<8, 256, 0, stream>>>(rowsumP, logz);
    k_logits<1><<<3136, 256, 0, stream>>>(srb, embb, rnv, nullptr, logz, out);
}

// Round 8
// 932.158 us; speedup vs baseline: 1.7323x; 1.1668x over previous
//
#include <hip/hip_runtime.h>
#include <math.h>

constexpr int V_ = 50000, D_ = 128, B_ = 1024, P_ = 50;
constexpr int N_ = 51200, E_ = 51200;
constexpr long long NS_ = (long long)N_ * D_;
constexpr float SCALE_ = 12.0f;
constexpr int NBN_L = (V_ + 127) / 128;   // 391
constexpr int NBN_P = 392;                // padded row stride for partials

typedef unsigned short u16;
typedef __attribute__((ext_vector_type(8))) unsigned short u16x8;
typedef __attribute__((ext_vector_type(8))) __bf16 bf16x8;
typedef __attribute__((ext_vector_type(4))) float f32x4;

static __device__ __forceinline__ float wsum(float v) {
    #pragma unroll
    for (int o = 32; o; o >>= 1) v += __shfl_xor(v, o, 64);
    return v;
}
static __device__ __forceinline__ float wmax(float v) {
    #pragma unroll
    for (int o = 32; o; o >>= 1) v = fmaxf(v, __shfl_xor(v, o, 64));
    return v;
}
// fast transcendentals (hardware v_exp_f32 path)
static __device__ __forceinline__ float fsig(float x) { return 1.f / (1.f + __expf(-x)); }
static __device__ __forceinline__ float ftanh(float x) { return 2.f / (1.f + __expf(-2.f * x)) - 1.f; }
static __device__ __forceinline__ u16 f2b(float x) {
    unsigned u = __float_as_uint(x);
    u += 0x7fffu + ((u >> 16) & 1u);
    return (u16)(u >> 16);
}
static __device__ __forceinline__ float b2f(u16 u) {
    return __uint_as_float(((unsigned)u) << 16);
}
// reduce over the 16 lr-lanes of each 16-lane group
static __device__ __forceinline__ float redlr(float v) {
    v += __shfl_xor(v, 1, 64); v += __shfl_xor(v, 2, 64);
    v += __shfl_xor(v, 4, 64); v += __shfl_xor(v, 8, 64);
    return v;
}

// ---------------- emb -> bf16 + rnv ----------------
__global__ void k_embcv(const float* __restrict__ emb, u16* __restrict__ embb,
                        float* __restrict__ rnv) {
    int row = blockIdx.x * 4 + (threadIdx.x >> 6);
    if (row >= V_) return;
    int l = threadIdx.x & 63;
    const float* p = emb + (long long)row * D_;
    float a = p[l], b = p[l + 64];
    float ss = wsum(a * a + b * b);
    if (l == 0) rnv[row] = 1.f / (sqrtf(ss) + 1e-12f);
    u16* q = embb + (long long)row * D_;
    q[l] = f2b(a); q[l + 64] = f2b(b);
}

// ---------------- dt = max(edge_t) ----------------
__global__ void k_dtmax(const float* __restrict__ et, float* __restrict__ dt) {
    __shared__ float s[1024];
    float m = 0.f;
    for (int i = threadIdx.x; i < E_; i += 1024) m = fmaxf(m, et[i]);
    s[threadIdx.x] = m; __syncthreads();
    for (int o = 512; o; o >>= 1) {
        if (threadIdx.x < o) s[threadIdx.x] = fmaxf(s[threadIdx.x], s[threadIdx.x + o]);
        __syncthreads();
    }
    if (threadIdx.x == 0) *dt = s[0];
}

// ---------------- feat0 ----------------
__global__ void k_feat0(const u16* __restrict__ embb, const float* __restrict__ rnv,
                        const int* __restrict__ iid,
                        float* __restrict__ feat, u16* __restrict__ featb) {
    int row = blockIdx.x * 4 + (threadIdx.x >> 6);
    int l = threadIdx.x & 63;
    int id = iid[row];
    const u16* p = embb + (long long)id * D_;
    float s = rnv[id];
    float a = b2f(p[l]) * s, b = b2f(p[l + 64]) * s;
    float* q = feat + (long long)row * D_;
    q[l] = a; q[l + 64] = b;
    u16* qb = featb + (long long)row * D_;
    qb[l] = f2b(a); qb[l + 64] = f2b(b);
}

// ---------------- stage-A per-graph weighted aggregation ----------------
__global__ void k_aggA_g(const int* __restrict__ esrc, const int* __restrict__ edst,
                         const float* __restrict__ ew, const u16* __restrict__ featb,
                         u16* __restrict__ m_in, u16* __restrict__ m_out) {
    __shared__ float sfeat[P_ * D_];
    __shared__ float smin[P_ * D_];
    __shared__ float smout[P_ * D_];
    __shared__ int ses[P_], sed[P_];
    __shared__ float sw[P_], swin[P_], swout[P_];
    int g = blockIdx.x, t = threadIdx.x;
    int n0 = g * P_;
    long long base = (long long)n0 * D_;
    for (int i = t; i < P_ * D_; i += 256) {
        sfeat[i] = b2f(featb[base + i]);
        smin[i] = 0.f; smout[i] = 0.f;
    }
    if (t < P_) {
        int E0 = g * P_ + t;
        ses[t] = esrc[E0] - n0;
        sed[t] = edst[E0] - n0;
        sw[t] = ew[E0];
    }
    __syncthreads();
    int d = t & 127;
    for (int e = 0; e < P_; e++) {
        int ls = ses[e], ld = sed[e];
        float w = sw[e];
        if (t < 128) smin[ld * D_ + d] += sfeat[ls * D_ + d] * w;
        else         smout[ls * D_ + d] += sfeat[ld * D_ + d] * w;
    }
    if (t < P_) {
        float wi = 0.f, wo = 0.f;
        for (int e = 0; e < P_; e++) {
            if (sed[e] == t) wi += sw[e];
            if (ses[e] == t) wo += sw[e];
        }
        swin[t] = (wi > 0.f) ? 1.f / wi : 1.f;
        swout[t] = (wo > 0.f) ? 1.f / wo : 1.f;
    }
    __syncthreads();
    for (int i = t; i < P_ * D_; i += 256) {
        int n = i >> 7;
        m_in[base + i] = f2b(smin[i] * swin[n]);
        m_out[base + i] = f2b(smout[i] * swout[n]);
    }
}

// ---------------- per-graph GCN aggregation (LDS CSR gather) ----------------
template<int MODE>
__launch_bounds__(256)
__global__ void k_gagg2(const int* __restrict__ esrc, const int* __restrict__ edst,
                        const float* __restrict__ et, const float* __restrict__ dtp, float tfac,
                        const u16* __restrict__ a1, int s1,
                        const u16* __restrict__ a2, int s2,
                        u16* __restrict__ out1, u16* __restrict__ out2) {
    constexpr int NSV = (MODE == 0) ? 2 : 1;
    __shared__ float sv[NSV * P_ * D_];
    __shared__ int ses[P_], sed[P_];
    __shared__ float snrm[P_];
    __shared__ int sdeg[P_], soff[P_ + 1];
    __shared__ int snbr[2 * P_];
    int g = blockIdx.x, t = threadIdx.x;
    int n0 = g * P_;
    long long base = (long long)n0 * D_;
    float tv = tfac * dtp[0];
    if (t < P_) {
        int E0 = g * P_ + t;
        int s = esrc[E0], dd = edst[E0];
        bool ml = (s != dd) && (et[E0] <= tv);
        ses[t] = ml ? (s - n0) : -1;
        sed[t] = ml ? (dd - n0) : -1;
    }
    __syncthreads();
    if (t < P_) {
        int deg = 0;
        for (int e = 0; e < P_; e++) deg += (ses[e] == t) + (sed[e] == t);
        sdeg[t] = deg;
        snrm[t] = rsqrtf(fmaxf((float)deg, 1.f));
    }
    __syncthreads();
    if (t == 0) {
        int off = 0;
        for (int n = 0; n < P_; n++) { soff[n] = off; off += sdeg[n]; }
        soff[P_] = off;
    }
    __syncthreads();
    if (t < P_) {
        int c = soff[t];
        for (int e = 0; e < P_; e++) {
            if (ses[e] == t) snbr[c++] = sed[e];
            if (sed[e] == t) snbr[c++] = ses[e];
        }
    }
    float* sv1 = sv;
    float* sv2 = sv + (NSV - 1) * P_ * D_;
    for (int i = t; i < P_ * D_; i += 256) {
        int n = i >> 7, d = i & 127;
        if (MODE == 1) {
            sv1[i] = b2f(a1[(long long)(n0 + n) * s1 + d]) *
                     b2f(a2[(long long)(n0 + n) * s2 + d]) * snrm[n];
        } else {
            sv1[i] = a1 ? b2f(a1[(long long)(n0 + n) * s1 + d]) * snrm[n] : 0.f;
            if (a2) sv2[i] = b2f(a2[(long long)(n0 + n) * s2 + d]) * snrm[n];
        }
    }
    __syncthreads();
    int d = t & 127;
    int nlo = (t >> 7) * 25;
    bool two = (MODE == 0) && (a2 != nullptr);
    for (int n = nlo; n < nlo + 25; n++) {
        float s1a = 0.f, s2a = 0.f;
        int j0 = soff[n], j1 = soff[n + 1];
        for (int j = j0; j < j1; j++) {
            int nb = snbr[j];
            s1a += sv1[nb * D_ + d];
            if (two) s2a += sv2[nb * D_ + d];
        }
        float nr = snrm[n];
        long long o = base + (long long)n * D_ + d;
        out1[o] = f2b(s1a * nr);
        if (two) out2[o] = f2b(s2a * nr);
    }
}

// ---------------- merged weight precompute ----------------
__global__ void k_prec_all(const float* __restrict__ W1, const float* __restrict__ W2,
                           const float* __restrict__ wih, const float* __restrict__ whh,
                           const float* __restrict__ bih, const float* __restrict__ bhh,
                           const float* __restrict__ Wxr, const float* __restrict__ Wxz,
                           const float* __restrict__ Whr, const float* __restrict__ Whz,
                           const float* __restrict__ bxr, const float* __restrict__ bxz,
                           const float* __restrict__ bhr, const float* __restrict__ bhz,
                           const float* __restrict__ Wxh, const float* __restrict__ Whh,
                           const float* __restrict__ bxh, const float* __restrict__ bhh2,
                           const float* __restrict__ fcu,
                           u16* __restrict__ BM1t, u16* __restrict__ BM2t, u16* __restrict__ BM3t,
                           u16* __restrict__ Brz1, u16* __restrict__ Brz2,
                           u16* __restrict__ Bu1, u16* __restrict__ Bu2, u16* __restrict__ Bfc,
                           float* __restrict__ b512, float* __restrict__ brz,
                           float* __restrict__ bu) {
    int blk = blockIdx.x, t = threadIdx.x;
    if (blk < 512) {
        const float* W = (blk < 256) ? W1 : W2;
        int coff = (blk < 256) ? 0 : 256;
        u16* Bt = (blk < 256) ? BM1t : BM2t;
        int idx = (blk & 255) * 256 + t;
        int j = idx >> 7, k = idx & 127;
        float s = 0.f;
        if (j < 384) {
            const float* wr = W + (long long)k * 256;
            const float* ir = wih + (long long)j * 512 + coff;
            for (int c = 0; c < 256; c++) s += wr[c] * ir[c];
        }
        Bt[idx] = f2b(s);
    } else if (blk < 768) {
        int idx = (blk - 512) * 256 + t;
        int j = idx >> 7, k = idx & 127;
        float v = 0.f;
        if (j < 256) v = whh[(long long)j * 128 + k];
        else if (j >= 384) v = whh[(long long)(j - 128) * 128 + k];
        BM3t[idx] = f2b(v);
    } else if (blk < 896) {
        int idx = (blk - 768) * 256 + t;
        int c = idx >> 7, k = idx & 127;
        float v1 = (c < 128) ? Wxr[(long long)k * 128 + c] : Wxz[(long long)k * 128 + (c - 128)];
        float v2 = (c < 128) ? Whr[(long long)k * 128 + c] : Whz[(long long)k * 128 + (c - 128)];
        Brz1[idx] = f2b(v1); Brz2[idx] = f2b(v2);
        if (k == 0) brz[c] = (c < 128) ? bxr[c] + bhr[c] : bxz[c - 128] + bhz[c - 128];
    } else if (blk < 960) {
        int idx = (blk - 896) * 256 + t;
        int c = idx >> 7, k = idx & 127;
        Bu1[idx] = f2b(Wxh[(long long)k * 128 + c]);
        Bu2[idx] = f2b(Whh[(long long)k * 128 + c]);
        if (k == 0) bu[c] = bxh[c] + bhh2[c];
    } else if (blk < 1024) {
        int idx = (blk - 960) * 256 + t;
        int c = idx >> 7, k = idx & 127;
        Bfc[idx] = f2b(fcu[(long long)k * 128 + c]);
    } else {
        int j = (blk - 1024) * 256 + t;
        if (j < 512) {
            float v;
            if (j < 256) v = bih[j] + bhh[j];
            else if (j < 384) v = bih[j];
            else v = bhh[j - 128];
            b512[j] = v;
        }
    }
}

// ---------------- bf16 MFMA GEMM ----------------
template<int NSEG, int ACT>
__launch_bounds__(256)
__global__ void k_mm(const u16* __restrict__ A1, const u16* __restrict__ A2,
                     const u16* __restrict__ A3,
                     const u16* __restrict__ B1, const u16* __restrict__ B2,
                     const u16* __restrict__ B3,
                     const float* __restrict__ bias,
                     u16* __restrict__ C, int ldc, int nbn) {
    __shared__ u16 As[128 * 40];
    __shared__ u16 Bs[128 * 40];
    const int t = threadIdx.x;
    const int bid = blockIdx.x;
    const int xcd = bid & 7, idx = bid >> 3;
    const int nbm8 = gridDim.x / (8 * nbn);
    const int bm = xcd * nbm8 + idx / nbn;
    const int bn = idx % nbn;
    const int lane = t & 63, wid = t >> 6;
    const int wr = wid >> 1, wc = wid & 1;
    const int lr = lane & 15, lh = lane >> 4;
    f32x4 acc[4][4] = {};
    constexpr int KTOT = NSEG * 128;
    for (int ks = 0; ks < KTOT; ks += 32) {
        const u16* Ap = (NSEG == 1) ? A1 : (ks < 128 ? A1 : (ks < 256 ? A2 : A3));
        const u16* Bp = (NSEG == 1) ? B1 : (ks < 128 ? B1 : (ks < 256 ? B2 : B3));
        int kk = ks & 127;
        #pragma unroll
        for (int i = 0; i < 2; i++) {
            int id2 = i * 256 + t;
            int row = id2 >> 2, kl = (id2 & 3) * 8;
            u16x8 va = *(const u16x8*)&Ap[((long long)bm * 128 + row) * 128 + kk + kl];
            *(u16x8*)&As[row * 40 + kl] = va;
            u16x8 vb = *(const u16x8*)&Bp[((long long)bn * 128 + row) * 128 + kk + kl];
            *(u16x8*)&Bs[row * 40 + kl] = vb;
        }
        __syncthreads();
        bf16x8 af[4], bf[4];
        #pragma unroll
        for (int f = 0; f < 4; f++) {
            u16x8 ar = *(const u16x8*)&As[(wr * 64 + f * 16 + lr) * 40 + lh * 8];
            u16x8 br = *(const u16x8*)&Bs[(wc * 64 + f * 16 + lr) * 40 + lh * 8];
            af[f] = __builtin_bit_cast(bf16x8, ar);
            bf[f] = __builtin_bit_cast(bf16x8, br);
        }
        #pragma unroll
        for (int fr = 0; fr < 4; fr++)
            #pragma unroll
            for (int fc = 0; fc < 4; fc++)
                acc[fr][fc] = __builtin_amdgcn_mfma_f32_16x16x32_bf16(af[fr], bf[fc], acc[fr][fc], 0, 0, 0);
        __syncthreads();
    }
    #pragma unroll
    for (int fc = 0; fc < 4; fc++) {
        int col = bn * 128 + wc * 64 + fc * 16 + lr;
        float bb = bias ? bias[col] : 0.f;
        #pragma unroll
        for (int fr = 0; fr < 4; fr++) {
            int rowl = wr * 64 + fr * 16 + lh * 4;
            long long row0 = (long long)bm * 128 + rowl;
            #pragma unroll
            for (int r = 0; r < 4; r++) {
                float v = acc[fr][fc][r] + bb;
                if (ACT == 1) v = fsig(v);
                else if (ACT == 2) v = ftanh(v);
                C[(row0 + r) * (long long)ldc + col] = f2b(v);
            }
        }
    }
}

// ---------------- u-GEMM fused with dh/acc/h update; FIN folds k_fin ----------
// hprev: stage state h (read). hout: write target (Hb for stages, FEATb for FIN).
template<int FIN>
__launch_bounds__(256)
__global__ void k_u_dhu(const u16* __restrict__ A1, const u16* __restrict__ A2,
                        const u16* __restrict__ B1, const u16* __restrict__ B2,
                        const float* __restrict__ bias,
                        const u16* __restrict__ RZ, const u16* __restrict__ featb,
                        const float* __restrict__ feat32,
                        const u16* __restrict__ hprev,
                        float* __restrict__ acc_g, u16* __restrict__ hout,
                        const float* __restrict__ dtp, float accw, float hfac, int first) {
    __shared__ u16 As[128 * 40];
    __shared__ u16 Bs[128 * 40];
    __shared__ float ssqW[2][128];
    const int t = threadIdx.x;
    const int bm = blockIdx.x;
    const int lane = t & 63, wid = t >> 6;
    const int wr = wid >> 1, wc = wid & 1;
    const int lr = lane & 15, lh = lane >> 4;
    f32x4 acc[4][4] = {};
    for (int ks = 0; ks < 256; ks += 32) {
        const u16* Ap = (ks < 128) ? A1 : A2;
        const u16* Bp = (ks < 128) ? B1 : B2;
        int kk = ks & 127;
        #pragma unroll
        for (int i = 0; i < 2; i++) {
            int id2 = i * 256 + t;
            int row = id2 >> 2, kl = (id2 & 3) * 8;
            u16x8 va = *(const u16x8*)&Ap[((long long)bm * 128 + row) * 128 + kk + kl];
            *(u16x8*)&As[row * 40 + kl] = va;
            u16x8 vb = *(const u16x8*)&Bp[(long long)row * 128 + kk + kl];
            *(u16x8*)&Bs[row * 40 + kl] = vb;
        }
        __syncthreads();
        bf16x8 af[4], bf[4];
        #pragma unroll
        for (int f = 0; f < 4; f++) {
            u16x8 ar = *(const u16x8*)&As[(wr * 64 + f * 16 + lr) * 40 + lh * 8];
            u16x8 br = *(const u16x8*)&Bs[(wc * 64 + f * 16 + lr) * 40 + lh * 8];
            af[f] = __builtin_bit_cast(bf16x8, ar);
            bf[f] = __builtin_bit_cast(bf16x8, br);
        }
        #pragma unroll
        for (int fr = 0; fr < 4; fr++)
            #pragma unroll
            for (int fc = 0; fc < 4; fc++)
                acc[fr][fc] = __builtin_amdgcn_mfma_f32_16x16x32_bf16(af[fr], bf[fc], acc[fr][fc], 0, 0, 0);
        __syncthreads();
    }
    float pr[4][4] = {};
    #pragma unroll
    for (int fc = 0; fc < 4; fc++) {
        int col = wc * 64 + fc * 16 + lr;
        float bb = bias[col];
        #pragma unroll
        for (int fr = 0; fr < 4; fr++) {
            int rowl = wr * 64 + fr * 16 + lh * 4;
            #pragma unroll
            for (int r = 0; r < 4; r++) {
                long long row = (long long)bm * 128 + rowl + r;
                float u = ftanh(acc[fr][fc][r] + bb);
                float z = b2f(RZ[row * 256 + 128 + col]);
                float hh = b2f(hprev[row * 128 + col]);
                float v = (1.f - z) * (u - hh);
                acc[fr][fc][r] = v;
                pr[fr][r] += v * v;
            }
        }
    }
    // shuffle-reduce over the 16 lr-lanes; one plain LDS write per group
    #pragma unroll
    for (int fr = 0; fr < 4; fr++)
        #pragma unroll
        for (int r = 0; r < 4; r++) {
            float v = redlr(pr[fr][r]);
            if (lr == 0) ssqW[wc][wr * 64 + fr * 16 + lh * 4 + r] = v;
        }
    __syncthreads();
    float dt = dtp[0];
    if (FIN) {
        float dt6 = dt / 6.f;
        float pr2[4][4] = {};
        #pragma unroll
        for (int fr = 0; fr < 4; fr++) {
            int rowl0 = wr * 64 + fr * 16 + lh * 4;
            #pragma unroll
            for (int r = 0; r < 4; r++) {
                float s = 1.f / fmaxf(sqrtf(ssqW[0][rowl0 + r] + ssqW[1][rowl0 + r]), 1e-12f);
                long long row = (long long)bm * 128 + rowl0 + r;
                #pragma unroll
                for (int fc = 0; fc < 4; fc++) {
                    int col = wc * 64 + fc * 16 + lr;
                    long long ix = row * 128 + col;
                    float kv = acc[fr][fc][r] * s;
                    float an = acc_g[ix] + accw * kv;          // final RK4 acc
                    float fv2 = feat32[ix] + dt6 * an;
                    acc[fr][fc][r] = fv2;
                    pr2[fr][r] += fv2 * fv2;
                }
            }
        }
        __syncthreads();   // all ssqW reads complete before overwrite
        #pragma unroll
        for (int fr = 0; fr < 4; fr++)
            #pragma unroll
            for (int r = 0; r < 4; r++) {
                float v = redlr(pr2[fr][r]);
                if (lr == 0) ssqW[wc][wr * 64 + fr * 16 + lh * 4 + r] = v;
            }
        __syncthreads();
        #pragma unroll
        for (int fr = 0; fr < 4; fr++) {
            int rowl0 = wr * 64 + fr * 16 + lh * 4;
            #pragma unroll
            for (int r = 0; r < 4; r++) {
                float s2 = 1.f / sqrtf(ssqW[0][rowl0 + r] + ssqW[1][rowl0 + r]);
                long long row = (long long)bm * 128 + rowl0 + r;
                #pragma unroll
                for (int fc = 0; fc < 4; fc++) {
                    int col = wc * 64 + fc * 16 + lr;
                    hout[row * 128 + col] = f2b(acc[fr][fc][r] * s2);
                }
            }
        }
    } else {
        #pragma unroll
        for (int fr = 0; fr < 4; fr++) {
            int rowl0 = wr * 64 + fr * 16 + lh * 4;
            #pragma unroll
            for (int r = 0; r < 4; r++) {
                float s = 1.f / fmaxf(sqrtf(ssqW[0][rowl0 + r] + ssqW[1][rowl0 + r]), 1e-12f);
                long long row = (long long)bm * 128 + rowl0 + r;
                #pragma unroll
                for (int fc = 0; fc < 4; fc++) {
                    int col = wc * 64 + fc * 16 + lr;
                    long long ix = row * 128 + col;
                    float kv = acc[fr][fc][r] * s;
                    float an = (first ? 0.f : acc_g[ix]) + accw * kv;
                    acc_g[ix] = an;
                    hout[ix] = f2b(b2f(featb[ix]) + hfac * dt * kv);
                }
            }
        }
    }
}

// ---------------- GRU + renorm (also seeds H = feat) ----------------
__global__ void k_gru2(const u16* __restrict__ gih, float* __restrict__ feat,
                       u16* __restrict__ featb, u16* __restrict__ hb) {
    int row = blockIdx.x * 4 + (threadIdx.x >> 6);
    int l = threadIdx.x & 63;
    const u16* g = gih + (long long)row * 512;
    float* fr = feat + (long long)row * 128;
    float nv[2]; float ss = 0.f;
    #pragma unroll
    for (int tq = 0; tq < 2; tq++) {
        int d = l + tq * 64;
        float r = fsig(b2f(g[d]));
        float z = fsig(b2f(g[128 + d]));
        float n = ftanh(b2f(g[256 + d]) + r * b2f(g[384 + d]));
        float fv = fr[d];
        nv[tq] = (1.f - z) * n + z * fv;
        ss += nv[tq] * nv[tq];
    }
    ss = wsum(ss);
    float s = 1.f / fmaxf(sqrtf(ss), 1e-12f);
    float a = nv[0] * s, b = nv[1] * s;
    fr[l] = a; fr[l + 64] = b;
    u16 ab = f2b(a), bb = f2b(b);
    u16* fb = featb + (long long)row * 128;
    fb[l] = ab; fb[l + 64] = bb;
    u16* hh = hb + (long long)row * 128;
    hh[l] = ab; hh[l + 64] = bb;
}

// ---------------- fused readout: fv + e + softmax + srg + sr ----------------
__launch_bounds__(256)
__global__ void k_readout(const u16* __restrict__ featb, const u16* __restrict__ FU,
                          const int* __restrict__ last,
                          const float* __restrict__ fvw, const float* __restrict__ fvbv,
                          const float* __restrict__ fce, const float* __restrict__ fsr,
                          u16* __restrict__ srb) {
    __shared__ float sfl[128], sfv[128], se[64], sal[64], sin2[256], red[2];
    int g = blockIdx.x, t = threadIdx.x;
    int n0 = g * P_;
    long long ln = last[g];
    if (t < 128) sfl[t] = b2f(featb[ln * 128 + t]);
    __syncthreads();
    if (t < 128) {
        float s = fvbv[t];
        for (int k = 0; k < 128; k++) s += sfl[k] * fvw[(long long)k * 128 + t];
        sfv[t] = s;
        sin2[t] = sfl[t];
    }
    __syncthreads();
    int wid = t >> 6, lane = t & 63;
    float fce0 = fce[lane], fce1 = fce[lane + 64];
    for (int p = wid; p < P_; p += 4) {
        const u16* fu = FU + (long long)(n0 + p) * 128;
        float x0 = b2f(fu[lane]) + sfv[lane];
        float x1 = b2f(fu[lane + 64]) + sfv[lane + 64];
        float s = fsig(x0) * fce0 + fsig(x1) * fce1;
        s = wsum(s);
        if (lane == 0) se[p] = s;
    }
    __syncthreads();
    if (t < 64) {
        float v = (t < P_) ? se[t] : -1e30f;
        float m = wmax(v);
        float ex = (t < P_) ? __expf(v - m) : 0.f;
        float ss = wsum(ex);
        if (t < P_) sal[t] = ex / ss;
    }
    __syncthreads();
    if (t < 128) {
        float s = 0.f;
        for (int p = 0; p < P_; p++)
            s += b2f(featb[(long long)(n0 + p) * 128 + t]) * sal[p];
        sin2[128 + t] = s;
    }
    __syncthreads();
    if (t < 128) {
        float s = 0.f;
        for (int k = 0; k < 256; k++) s += sin2[k] * fsr[(long long)k * 128 + t];
        float ss = wsum(s * s);
        if (lane == 0) red[t >> 6] = ss;
        __syncthreads();
        float nrm = sqrtf(red[0] + red[1]);
        srb[(long long)g * 128 + t] = f2b(s / (nrm + 1e-12f));
    } else {
        __syncthreads();
    }
}

// ---------------- logits + fixed-shift log-softmax (|logit| <= 12) ----------------
// PASS0: partial exp-sums -> rowsumP[row][bn] (shuffle-reduced, no atomics).
// PASS1: out = logit - 12 - logZ[row].
template<int PASS>
__launch_bounds__(256)
__global__ void k_logits(const u16* __restrict__ A, const u16* __restrict__ Bt,
                         const float* __restrict__ rnv, float* __restrict__ rowsumP,
                         const float* __restrict__ logz, float* __restrict__ C) {
    __shared__ u16 As[128 * 40];
    __shared__ u16 Bs[128 * 40];
    __shared__ float sredW[2][128];
    const int t = threadIdx.x;
    const int bid = blockIdx.x;
    const int xcd = bid & 7, idx = bid >> 3;
    const int bm = idx & 7, bnl = idx >> 3;
    const int bn = xcd * 49 + bnl;
    if (bn >= NBN_L) return;
    const int lane = t & 63, wid = t >> 6;
    const int wr = wid >> 1, wc = wid & 1;
    const int lr = lane & 15, lh = lane >> 4;
    f32x4 acc[4][4] = {};
    for (int ks = 0; ks < 128; ks += 32) {
        #pragma unroll
        for (int i = 0; i < 2; i++) {
            int id2 = i * 256 + t;
            int row = id2 >> 2, kl = (id2 & 3) * 8;
            u16x8 va = *(const u16x8*)&A[((long long)bm * 128 + row) * 128 + ks + kl];
            *(u16x8*)&As[row * 40 + kl] = va;
            long long gcol = (long long)bn * 128 + row;
            u16x8 vb;
            if (gcol < V_) vb = *(const u16x8*)&Bt[gcol * 128 + ks + kl];
            else vb = u16x8{0, 0, 0, 0, 0, 0, 0, 0};
            *(u16x8*)&Bs[row * 40 + kl] = vb;
        }
        __syncthreads();
        bf16x8 af[4], bf[4];
        #pragma unroll
        for (int f = 0; f < 4; f++) {
            u16x8 ar = *(const u16x8*)&As[(wr * 64 + f * 16 + lr) * 40 + lh * 8];
            u16x8 br = *(const u16x8*)&Bs[(wc * 64 + f * 16 + lr) * 40 + lh * 8];
            af[f] = __builtin_bit_cast(bf16x8, ar);
            bf[f] = __builtin_bit_cast(bf16x8, br);
        }
        #pragma unroll
        for (int fr = 0; fr < 4; fr++)
            #pragma unroll
            for (int fc = 0; fc < 4; fc++)
                acc[fr][fc] = __builtin_amdgcn_mfma_f32_16x16x32_bf16(af[fr], bf[fc], acc[fr][fc], 0, 0, 0);
        __syncthreads();
    }
    if (PASS == 0) {
        float pr[4][4] = {};
        #pragma unroll
        for (int fc = 0; fc < 4; fc++) {
            int col = bn * 128 + wc * 64 + fc * 16 + lr;
            if (col >= V_) continue;
            float cs = rnv[col] * SCALE_;
            #pragma unroll
            for (int fr = 0; fr < 4; fr++)
                #pragma unroll
                for (int r = 0; r < 4; r++)
                    pr[fr][r] += __expf(acc[fr][fc][r] * cs - SCALE_);
        }
        #pragma unroll
        for (int fr = 0; fr < 4; fr++)
            #pragma unroll
            for (int r = 0; r < 4; r++) {
                float v = redlr(pr[fr][r]);
                if (lr == 0) sredW[wc][wr * 64 + fr * 16 + lh * 4 + r] = v;
            }
        __syncthreads();
        if (t < 128) rowsumP[(long long)(bm * 128 + t) * NBN_P + bn] = sredW[0][t] + sredW[1][t];
    } else {
        if (t < 128) sredW[0][t] = logz[bm * 128 + t];
        __syncthreads();
        #pragma unroll
        for (int fc = 0; fc < 4; fc++) {
            int col = bn * 128 + wc * 64 + fc * 16 + lr;
            if (col >= V_) continue;
            float cs = rnv[col] * SCALE_;
            #pragma unroll
            for (int fr = 0; fr < 4; fr++) {
                int rowl = wr * 64 + fr * 16 + lh * 4;
                long long row0 = (long long)bm * 128 + rowl;
                #pragma unroll
                for (int r = 0; r < 4; r++)
                    C[(row0 + r) * (long long)V_ + col] = acc[fr][fc][r] * cs - SCALE_ - sredW[0][rowl + r];
            }
        }
    }
}

// reduce partials: logz[row] = log( sum_j rowsumP[row][j] )
__global__ void k_rsum(const float* __restrict__ rowsumP, float* __restrict__ logz) {
    int t = threadIdx.x;
    int row = blockIdx.x * 128 + (t >> 1);
    int half = t & 1;
    const float* p = rowsumP + (long long)row * NBN_P;
    float s = 0.f;
    int j0 = half ? 196 : 0, j1 = half ? NBN_L : 196;
    for (int j = j0; j < j1; j++) s += p[j];
    s += __shfl_xor(s, 1);
    if (!half) logz[row] = logf(s);
}

// ================= host orchestration =================
extern "C" void kernel_launch(void* const* d_in, const int* in_sizes, int n_in,
                              void* d_out, int out_size, void* d_ws, size_t ws_size,
                              hipStream_t stream) {
    const int* iid   = (const int*)d_in[0];
    const int* esrc  = (const int*)d_in[1];
    const int* edst  = (const int*)d_in[2];
    const int* last  = (const int*)d_in[4];
    const float* ew  = (const float*)d_in[5];
    const float* et  = (const float*)d_in[6];
    const float* emb = (const float*)d_in[7];
    const float* W1  = (const float*)d_in[8];
    const float* W2  = (const float*)d_in[9];
    const float* wih = (const float*)d_in[10];
    const float* whh = (const float*)d_in[11];
    const float* bih = (const float*)d_in[12];
    const float* bhh = (const float*)d_in[13];
    const float* Wxr = (const float*)d_in[14]; const float* bxr = (const float*)d_in[15];
    const float* Wxz = (const float*)d_in[16]; const float* bxz = (const float*)d_in[17];
    const float* Wxh = (const float*)d_in[18]; const float* bxh = (const float*)d_in[19];
    const float* Whr = (const float*)d_in[20]; const float* bhr = (const float*)d_in[21];
    const float* Whz = (const float*)d_in[22]; const float* bhz = (const float*)d_in[23];
    const float* Whh = (const float*)d_in[24]; const float* bhh2 = (const float*)d_in[25];
    const float* fcu = (const float*)d_in[26];
    const float* fvw = (const float*)d_in[27]; const float* fvbv = (const float*)d_in[28];
    const float* fce = (const float*)d_in[29];
    const float* fsr = (const float*)d_in[30];
    float* out = (float*)d_out;

    char* w = (char*)d_ws;
    auto alloc = [&](size_t bytes) { char* p = w; w += (bytes + 255) & ~(size_t)255; return p; };
    float* FEAT  = (float*)alloc(NS_ * 4);
    float* ACC   = (float*)alloc(NS_ * 4);
    u16* FEATb   = (u16*)alloc(NS_ * 2);
    u16* Hb      = (u16*)alloc(NS_ * 2);
    u16* MINb    = (u16*)alloc(NS_ * 2);
    u16* MOUTb   = (u16*)alloc(NS_ * 2);
    u16* GIHb    = (u16*)alloc(NS_ * 8);    // N x 512
    u16* AXb     = GIHb;
    u16* AHb     = GIHb + NS_;
    u16* RZb     = GIHb + 2 * NS_;          // N x 256
    u16* FUb     = MINb;                    // MINb dead after GIH gemm
    u16* embb    = (u16*)alloc((long long)V_ * 128 * 2);
    u16* srb     = (u16*)alloc(B_ * 128 * 2);
    u16* BM1t    = (u16*)alloc(512 * 128 * 2);
    u16* BM2t    = (u16*)alloc(512 * 128 * 2);
    u16* BM3t    = (u16*)alloc(512 * 128 * 2);
    u16* Brz1    = (u16*)alloc(256 * 128 * 2);
    u16* Brz2    = (u16*)alloc(256 * 128 * 2);
    u16* Bu1     = (u16*)alloc(128 * 128 * 2);
    u16* Bu2     = (u16*)alloc(128 * 128 * 2);
    u16* Bfc     = (u16*)alloc(128 * 128 * 2);
    float* b512  = (float*)alloc(512 * 4);
    float* brz   = (float*)alloc(256 * 4);
    float* bu    = (float*)alloc(128 * 4);
    float* dtp   = (float*)alloc(64 * 4);
    float* rnv   = (float*)alloc((long long)V_ * 4);
    float* rowsumP = (float*)alloc((long long)B_ * NBN_P * 4);
    float* logz  = (float*)alloc(B_ * 4);

    k_embcv<<<(V_ + 3) / 4, 256, 0, stream>>>(emb, embb, rnv);
    k_dtmax<<<1, 1024, 0, stream>>>(et, dtp);
    k_feat0<<<N_ / 4, 256, 0, stream>>>(embb, rnv, iid, FEAT, FEATb);

    // ---- stage A ----
    k_aggA_g<<<B_, 256, 0, stream>>>(esrc, edst, ew, FEATb, MINb, MOUTb);
    k_prec_all<<<1026, 256, 0, stream>>>(W1, W2, wih, whh, bih, bhh,
                                         Wxr, Wxz, Whr, Whz, bxr, bxz, bhr, bhz,
                                         Wxh, Whh, bxh, bhh2, fcu,
                                         BM1t, BM2t, BM3t, Brz1, Brz2, Bu1, Bu2, Bfc,
                                         b512, brz, bu);
    k_mm<3, 0><<<1600, 256, 0, stream>>>(MINb, MOUTb, FEATb, BM1t, BM2t, BM3t, b512, GIHb, 512, 4);
    k_gru2<<<N_ / 4, 256, 0, stream>>>(GIHb, FEAT, FEATb, Hb);

    // ---- stage B: RK4 ----
    auto fstep = [&](float tfac, int mode, float accw, float hfac, int first, int fin) {
        if (mode == 0)
            k_gagg2<0><<<B_, 256, 0, stream>>>(esrc, edst, et, dtp, tfac, FEATb, 128, nullptr, 0, AXb, nullptr);
        else if (mode == 1)
            k_gagg2<0><<<B_, 256, 0, stream>>>(esrc, edst, et, dtp, tfac, FEATb, 128, Hb, 128, AXb, AHb);
        else
            k_gagg2<0><<<B_, 256, 0, stream>>>(esrc, edst, et, dtp, tfac, Hb, 128, nullptr, 0, AHb, nullptr);
        const u16* AHp = (mode == 0) ? AXb : AHb;
        k_mm<2, 1><<<800, 256, 0, stream>>>(AXb, AHp, nullptr, Brz1, Brz2, nullptr, brz, RZb, 256, 2);
        k_gagg2<1><<<B_, 256, 0, stream>>>(esrc, edst, et, dtp, tfac, RZb, 256, Hb, 128, AHb, nullptr);
        if (fin)
            k_u_dhu<1><<<400, 256, 0, stream>>>(AXb, AHb, Bu1, Bu2, bu, RZb, FEATb, FEAT,
                                                Hb, ACC, FEATb, dtp, accw, hfac, first);
        else
            k_u_dhu<0><<<400, 256, 0, stream>>>(AXb, AHb, Bu1, Bu2, bu, RZb, FEATb, FEAT,
                                                Hb, ACC, Hb, dtp, accw, hfac, first);
    };

    fstep(0.0f, 0, 1.f, 0.5f, 1, 0);
    fstep(0.5f, 1, 2.f, 0.5f, 0, 0);
    fstep(0.5f, 2, 2.f, 1.0f, 0, 0);
    fstep(1.0f, 1, 1.f, 0.0f, 0, 1);   // fused k_fin: writes final normalized FEATb

    // ---- readout ----
    k_mm<1, 0><<<400, 256, 0, stream>>>(FEATb, nullptr, nullptr, Bfc, nullptr, nullptr,
                                        nullptr, FUb, 128, 1);
    k_readout<<<B_, 256, 0, stream>>>(FEATb, FUb, last, fvw, fvbv, fce, fsr, srb);

    k_logits<0><<<3136, 256, 0, stream>>>(srb, embb, rnv, rowsumP, nullptr, nullptr);
    k_rsum<<<8, 256, 0, stream>>>(rowsumP, logz);
    k_logits<1><<<3136, 256, 0, stream>>>(srb, embb, rnv, nullptr, logz, out);
}